// Round 1
// 358.801 us; speedup vs baseline: 1.0355x; 1.0355x over previous
//
#include <hip/hip_runtime.h>
#include <hip/hip_bf16.h>
#include <cstdint>
#include <cstddef>

#define DM 1024
#define NH 16
#define DH 64
#define BB 2
#define TQ 2048
#define TCACHE 2048
#define TKTOT 4096
#define MROWS 4096

typedef __attribute__((ext_vector_type(8))) short bf16x8;
typedef __attribute__((ext_vector_type(4))) short bf16x4;
typedef __attribute__((ext_vector_type(4))) float f32x4;

__device__ __forceinline__ short f2bf(float f) {
  union { float f; unsigned u; } v; v.f = f;
  unsigned r = v.u + 0x7fffu + ((v.u >> 16) & 1u);
  return (short)(r >> 16);
}

__device__ __forceinline__ float bf2f(short s) {
  union { unsigned u; float f; } v;
  v.u = ((unsigned)(unsigned short)s) << 16;
  return v.f;
}

__device__ __forceinline__ float exp2fast(float x) {
#if __has_builtin(__builtin_amdgcn_exp2f)
  return __builtin_amdgcn_exp2f(x);
#else
  return exp2f(x);
#endif
}

// pack two f32 -> two bf16 in one dword (RNE)
__device__ __forceinline__ unsigned pk2(float a, float b) {
#if __has_builtin(__builtin_amdgcn_cvt_pk_bf16_f32)
  typedef __bf16 bf2 __attribute__((ext_vector_type(2)));
  union { bf2 v; unsigned u; } cv;
  cv.v = __builtin_amdgcn_cvt_pk_bf16_f32(a, b);
  return cv.u;
#else
  return (unsigned)(unsigned short)f2bf(a) | ((unsigned)(unsigned short)f2bf(b) << 16);
#endif
}

// async global->LDS, 16B/lane. LDS dest must be wave-uniform base + lane*16;
// swizzle goes on the GLOBAL address only (m104/m108).
__device__ __forceinline__ void gld_lds16(const short* g, short* l) {
  __builtin_amdgcn_global_load_lds(
      (const __attribute__((address_space(1))) void*)((uintptr_t)g),
      (__attribute__((address_space(3))) void*)((uintptr_t)l), 16, 0, 0);
}

// ---------- prep kernels ----------

__global__ void k_cvt_x(const float* __restrict__ x, short* __restrict__ xb) {
  const size_t i = (size_t)blockIdx.x * 256 + threadIdx.x;
  const float4 v = ((const float4*)x)[i];
  short4 o;
  o.x = f2bf(v.x); o.y = f2bf(v.y); o.z = f2bf(v.z); o.w = f2bf(v.w);
  ((short4*)xb)[i] = o;
}

// W [K][N] f32 -> Wt bf16 [N][K], 4 weights via blockIdx.z
__global__ void k_transpose_w(const float* __restrict__ W0, const float* __restrict__ W1,
                              const float* __restrict__ W2, const float* __restrict__ W3,
                              short* __restrict__ Wt) {
  __shared__ short tile[32][33];
  const float* W = (blockIdx.z == 0) ? W0 : (blockIdx.z == 1) ? W1 : (blockIdx.z == 2) ? W2 : W3;
  short* dst = Wt + (size_t)blockIdx.z * DM * DM;
  const int k0 = blockIdx.y * 32, n0 = blockIdx.x * 32;
  const int tx = threadIdx.x & 31, ty = threadIdx.x >> 5;
#pragma unroll
  for (int r = 0; r < 4; r++) {
    const int k = ty + r * 8;
    tile[k][tx] = f2bf(W[(size_t)(k0 + k) * DM + n0 + tx]);
  }
  __syncthreads();
#pragma unroll
  for (int r = 0; r < 4; r++) {
    const int n = ty + r * 8;
    dst[(size_t)(n0 + n) * DM + k0 + tx] = tile[tx][n];
  }
}

// k_cache f32 -> bf16 Kb cache part only
__global__ void k_copy_kcache(const float* __restrict__ kc, short* __restrict__ Kb) {
  const size_t i = (size_t)blockIdx.x * 256 + threadIdx.x;
  const float4 v = ((const float4*)kc)[i];
  const size_t e = i * 4;
  const int dh = (int)(e & 63);
  const int t = (int)((e >> 6) & 2047);
  const int bh = (int)(e >> 17);
  short4 o;
  o.x = f2bf(v.x); o.y = f2bf(v.y); o.z = f2bf(v.z); o.w = f2bf(v.w);
  *(short4*)(Kb + ((size_t)bh * TKTOT + t) * DH + dh) = o;
}

// v_cache f32 -> transposed bf16 Vt[b,h,dh,t] cache part only
__global__ void k_copy_vcache(const float* __restrict__ vc, short* __restrict__ Vtb) {
  __shared__ short tile[64][65];  // [dh][t]
  const int bh = blockIdx.y;
  const int t0 = blockIdx.x * 64;
  const int tx = threadIdx.x & 15, ty = threadIdx.x >> 4;
  const float* src = vc + ((size_t)bh * TCACHE + t0) * DH;
#pragma unroll
  for (int r = 0; r < 4; r++) {
    const int t = ty + r * 16;
    const float4 v = *(const float4*)(src + (size_t)t * DH + tx * 4);
    tile[tx * 4 + 0][t] = f2bf(v.x);
    tile[tx * 4 + 1][t] = f2bf(v.y);
    tile[tx * 4 + 2][t] = f2bf(v.z);
    tile[tx * 4 + 3][t] = f2bf(v.w);
  }
  __syncthreads();
  short* vt = Vtb + (size_t)bh * DH * TKTOT + t0;
#pragma unroll
  for (int r = 0; r < 4; r++) {
    const int dh = ty + r * 16;
    short4 o;
    o.x = tile[dh][tx * 4 + 0];
    o.y = tile[dh][tx * 4 + 1];
    o.z = tile[dh][tx * 4 + 2];
    o.w = tile[dh][tx * 4 + 3];
    *(short4*)(vt + (size_t)dh * TKTOT + tx * 4) = o;
  }
}

// ---------- GEMM: C[M,N] = A[M,K] * Bt[N,K]^T + bias ----------
// 64x128 tile (M x N), BK=32, 256 threads (4 waves, 32x64 each).
// Double-buffered staging: next K-step's global_load_lds flies during compute.
__global__ __launch_bounds__(256) void k_gemm(
    const short* __restrict__ A, const short* __restrict__ Bt,
    const float* __restrict__ b0, const float* __restrict__ b1, const float* __restrict__ b2,
    const int is_qkv, float* __restrict__ fdst,
    short* __restrict__ Qb, short* __restrict__ Kb, short* __restrict__ Vtb) {
  const int z = is_qkv ? (int)blockIdx.z : 3;
  const short* Bz = Bt + (is_qkv ? (size_t)z * DM * DM : 0);
  const float* bias = (z == 0 || z == 3) ? b0 : (z == 1 ? b1 : b2);

  __shared__ short sA[2][64 * 32];   // 2 x 4KB
  __shared__ short sB[2][128 * 32];  // 2 x 8KB

  const int m0 = blockIdx.y * 64;
  const int n0 = blockIdx.x * 128;
  const int tid = threadIdx.x;
  const int wv = tid >> 6;
  const int lane = tid & 63;
  const int quad = lane >> 4;
  const int l16 = lane & 15;
  const int wm = (wv >> 1) * 32;
  const int wn = (wv & 1) * 64;

  const f32x4 zero = {0.f, 0.f, 0.f, 0.f};
  f32x4 acc[2][4];
#pragma unroll
  for (int i = 0; i < 2; i++)
#pragma unroll
    for (int j = 0; j < 4; j++) acc[i][j] = zero;

  // kt-invariant fragment read offsets (bytes): row*64 + swizzled-chunk*16
  const int sw = (quad ^ ((l16 >> 1) & 3)) << 4;
  const int afo = (wm + l16) * 64 + sw;
  const int bfo = (wn + l16) * 64 + sw;

#define STAGEG(k0_, b_)                                                        \
  do {                                                                         \
    {                                                                          \
      const int c = tid;                                                       \
      const int row = c >> 2, cs = c & 3;                                      \
      const int gc = cs ^ ((row >> 1) & 3);                                    \
      gld_lds16(A + (size_t)(m0 + row) * DM + (k0_) + gc * 8, &sA[b_][c * 8]); \
    }                                                                          \
    _Pragma("unroll") for (int s = 0; s < 2; s++) {                            \
      const int c = tid + s * 256;                                             \
      const int row = c >> 2, cs = c & 3;                                      \
      const int gc = cs ^ ((row >> 1) & 3);                                    \
      gld_lds16(Bz + (size_t)(n0 + row) * DM + (k0_) + gc * 8, &sB[b_][c * 8]); \
    }                                                                          \
  } while (0)

  STAGEG(0, 0);
  __syncthreads();
  int buf = 0;
  for (int k0 = 0; k0 < DM; k0 += 32) {
    if (k0 + 32 < DM) STAGEG(k0 + 32, buf ^ 1);
    const char* Ab = (const char*)&sA[0][0] + buf * 4096;
    const char* Bb = (const char*)&sB[0][0] + buf * 8192;
    bf16x8 af[2], bfv[4];
#pragma unroll
    for (int i = 0; i < 2; i++) af[i] = *(const bf16x8*)(Ab + afo + i * 1024);
#pragma unroll
    for (int j = 0; j < 4; j++) bfv[j] = *(const bf16x8*)(Bb + bfo + j * 1024);
#pragma unroll
    for (int i = 0; i < 2; i++)
#pragma unroll
      for (int j = 0; j < 4; j++)
        acc[i][j] = __builtin_amdgcn_mfma_f32_16x16x32_bf16(af[i], bfv[j], acc[i][j], 0, 0, 0);
    __syncthreads();
    buf ^= 1;
  }
#undef STAGEG

#pragma unroll
  for (int i = 0; i < 2; i++) {
#pragma unroll
    for (int j = 0; j < 4; j++) {
      const int gn = n0 + wn + j * 16 + l16;
      const float bb = bias[gn];
#pragma unroll
      for (int r = 0; r < 4; r++) {
        const int gm = m0 + wm + i * 16 + quad * 4 + r;
        const float v = acc[i][j][r] + bb;
        if (z == 3) {
          fdst[(size_t)gm * DM + gn] = v;
        } else {
          const int b_ = gm >> 11, t = gm & 2047;
          const int h_ = gn >> 6, dh = gn & 63;
          if (z == 0) {
            // fold softmax scale AND log2(e): 0.125 * 1.4426950409
            Qb[(((size_t)(b_ * NH + h_)) * TQ + t) * DH + dh] = f2bf(v * 0.18033688011f);
          } else if (z == 1) {
            Kb[(((size_t)(b_ * NH + h_)) * TKTOT + TCACHE + t) * DH + dh] = f2bf(v);
          } else {
            Vtb[(((size_t)(b_ * NH + h_)) * DH + dh) * TKTOT + TCACHE + t] = f2bf(v);
          }
        }
      }
    }
  }
}

// ---------- flash attention, S^T-layout, split-K, no-max softmax ----------
// grid (2 splits, 32 q-blocks, 32 bh); 64 q rows/block; wave w owns rows [q0+16w, +16).
// v2: (1) double-buffered K/V staging (T3 2-phase: next tile's global_load_lds
//     flies under current tile's compute; one barrier per tile);
//     (2) Q fragments loaded straight from global into registers (no sQ);
//     (3) P round-trips through a per-wave LDS scratch (ds_write_b64 x4 +
//     ds_read_b128 x2 per tile, XOR-swizzled, wave-private so no barrier,
//     DS ops are in-order per wave) so PV and l-accum use full-rate
//     16x16x32 MFMAs instead of half-rate 16x16x16_1k;
//     (4) all LDS addresses precomputed outside the loop, j/jd terms are
//     compile-time immediates -> near-zero VALU in the inner loop.
__global__ __launch_bounds__(256, 4) void k_attn(const short* __restrict__ Qb,
                                                 const short* __restrict__ Kb,
                                                 const short* __restrict__ Vtb,
                                                 float* __restrict__ Opart,
                                                 float* __restrict__ Lpart) {
  __shared__ short sK[2][64 * 64];  // [key][dh], chunk^(row&7) swizzle, 2x8KB
  __shared__ short sV[2][64 * 64];  // [dh][key], chunk^(row&7) swizzle, 2x8KB
  __shared__ short sP[4][16 * 64];  // per-wave [q16][key64], chunk^(l16&7) swizzle, 8KB

  const int split = (int)blockIdx.x;
  const int qx = 31 - (int)blockIdx.y;  // longest blocks first
  const int bh = (int)blockIdx.z;
  const int q0 = qx * 64;
  const int tid = threadIdx.x;
  const int w = tid >> 6;
  const int lane = tid & 63;
  const int quad = lane >> 4;
  const int l16 = lane & 15;
  const int m = l16 & 7;

  const int nkt = qx + 33;  // total key tiles for this q-block
  const int half = (nkt + 1) >> 1;
  const int kt0 = split ? half : 0;
  const int kt1 = split ? nkt : half;

  const short* Kg = Kb + (size_t)bh * TKTOT * DH;
  const short* Vtg = Vtb + (size_t)bh * DH * TKTOT;

  // staging source pointers (per-thread, kt-invariant part)
  const int c0 = tid, c1 = tid + 256;
  const int r0 = c0 >> 3, g0 = ((c0 & 7) ^ (r0 & 7)) * 8;
  const int r1 = c1 >> 3, g1 = ((c1 & 7) ^ (r1 & 7)) * 8;
  const short* Kst0 = Kg + (size_t)r0 * DH + g0;
  const short* Kst1 = Kg + (size_t)r1 * DH + g1;
  const short* Vst0 = Vtg + (size_t)r0 * TKTOT + g0;
  const short* Vst1 = Vtg + (size_t)r1 * TKTOT + g1;

  // Q fragments straight from global (one row per lane, 2x16B)
  const short* Qrow = Qb + ((size_t)bh * TQ + q0 + w * 16 + l16) * DH;
  const bf16x8 qf0 = *(const bf16x8*)(Qrow + quad * 8);
  const bf16x8 qf1 = *(const bf16x8*)(Qrow + 32 + quad * 8);

  // kt-invariant LDS byte offsets
  const char* sKc = (const char*)&sK[0][0];
  const char* sVc = (const char*)&sV[0][0];
  char* sPc = (char*)&sP[0][0] + w * 2048 + l16 * 128;
  const int kaddrA = l16 * 128 + ((quad ^ m) << 4);        // K frag, k-half 0
  const int kaddrB = l16 * 128 + (((4 + quad) ^ m) << 4);  // K frag, k-half 1
  const int vaddr0 = l16 * 128 + ((quad ^ m) << 4);        // V frag, jp=0
  const int vaddr1 = l16 * 128 + (((4 + quad) ^ m) << 4);  // V frag, jp=1
  const int pr0 = (quad ^ m) << 4;                         // P read, jp=0
  const int pr1 = ((4 + quad) ^ m) << 4;                   // P read, jp=1
  int pw[4];
#pragma unroll
  for (int j = 0; j < 4; j++)
    pw[j] = (((2 * j + (quad >> 1)) ^ m) << 4) + (quad & 1) * 8;  // P write, per j

  const short ONE = (short)0x3F80;
  const bf16x8 ones8 = {ONE, ONE, ONE, ONE, ONE, ONE, ONE, ONE};

  const f32x4 zero = {0.f, 0.f, 0.f, 0.f};
  f32x4 of_[4];  // O[q=quad*4+r][dh=jd*16+l16]
  f32x4 l_acc = zero;
#pragma unroll
  for (int jd = 0; jd < 4; jd++) of_[jd] = zero;

  const int qg = q0 + w * 16 + l16;  // this lane's q row (St layout: q = l16)

#define STAGE(t_, b_)                               \
  do {                                              \
    const size_t koff = (size_t)(t_) * 64 * DH;     \
    const size_t voff = (size_t)(t_) * 64;          \
    short* dK = &sK[b_][0];                         \
    short* dV = &sV[b_][0];                         \
    gld_lds16(Kst0 + koff, dK + c0 * 8);            \
    gld_lds16(Kst1 + koff, dK + c1 * 8);            \
    gld_lds16(Vst0 + voff, dV + c0 * 8);            \
    gld_lds16(Vst1 + voff, dV + c1 * 8);            \
  } while (0)

  STAGE(kt0, 0);
  __syncthreads();
  int buf = 0;

  for (int t = kt0; t < kt1; t++) {
    if (t + 1 < kt1) STAGE(t + 1, buf ^ 1);
    const char* kb = sKc + buf * 8192;
    const char* vbb = sVc + buf * 8192;

    // St = K * Q^T : sacc[j] holds St[key=j*16+quad*4+r][q=l16]
    f32x4 sacc[4];
    __builtin_amdgcn_s_setprio(1);
#pragma unroll
    for (int j = 0; j < 4; j++) {
      const bf16x8 kfA = *(const bf16x8*)(kb + kaddrA + j * 2048);
      const bf16x8 kfB = *(const bf16x8*)(kb + kaddrB + j * 2048);
      f32x4 s = zero;
      s = __builtin_amdgcn_mfma_f32_16x16x32_bf16(kfA, qf0, s, 0, 0, 0);
      s = __builtin_amdgcn_mfma_f32_16x16x32_bf16(kfB, qf1, s, 0, 0, 0);
      sacc[j] = s;
    }
    __builtin_amdgcn_s_setprio(0);

    const bool need_mask = (t == nkt - 1);  // only the diagonal tile
    const int j0 = t * 64;
#pragma unroll
    for (int jp = 0; jp < 2; jp++) {
#pragma unroll
      for (int jj = 0; jj < 2; jj++) {
        const int j = jp * 2 + jj;
        float p[4];
#pragma unroll
        for (int r = 0; r < 4; r++) {
          float s = sacc[j][r];
          if (need_mask) {
            const int kg = j0 + j * 16 + quad * 4 + r;
            s = (kg > qg + TCACHE) ? -1e30f : s;
          }
          p[r] = exp2fast(s);
        }
        uint2 pu;
        pu.x = pk2(p[0], p[1]);
        pu.y = pk2(p[2], p[3]);
        *(uint2*)(sPc + pw[j]) = pu;  // keys 16j+quad*4..+3 of row q=l16
      }
      // A-fragment: P[q=l16][k=32*jp+quad*8+i] (wave-private, DS in-order)
      const bf16x8 pa = *(const bf16x8*)(sPc + (jp ? pr1 : pr0));
      const int vao = jp ? vaddr1 : vaddr0;
      __builtin_amdgcn_s_setprio(1);
      l_acc = __builtin_amdgcn_mfma_f32_16x16x32_bf16(pa, ones8, l_acc, 0, 0, 0);
#pragma unroll
      for (int jd = 0; jd < 4; jd++) {
        const bf16x8 vf = *(const bf16x8*)(vbb + vao + jd * 2048);
        of_[jd] = __builtin_amdgcn_mfma_f32_16x16x32_bf16(pa, vf, of_[jd], 0, 0, 0);
      }
      __builtin_amdgcn_s_setprio(0);
    }
    __syncthreads();
    buf ^= 1;
  }
#undef STAGE

  // write partials: O[64q][64dh] f32 + l[64] f32
  const int pid = (bh * 32 + qx) * 2 + split;
  float* Op = Opart + (size_t)pid * 4096 + (w * 16) * 64;
#pragma unroll
  for (int r = 0; r < 4; r++)
#pragma unroll
    for (int jd = 0; jd < 4; jd++)
      Op[(quad * 4 + r) * 64 + jd * 16 + l16] = of_[jd][r];
  if (l16 == 0) {
#pragma unroll
    for (int r = 0; r < 4; r++)
      Lpart[pid * 64 + w * 16 + quad * 4 + r] = l_acc[r];
  }
}

// ---------- reduce: combine 2 splits, normalize, write AOb bf16 ----------
__global__ __launch_bounds__(256) void k_reduce(const float* __restrict__ Opart,
                                                const float* __restrict__ Lpart,
                                                short* __restrict__ AOb) {
  const int qx = (int)blockIdx.x, bh = (int)blockIdx.y;
  const int b = bh >> 4, h = bh & 15;
  const int pid = (bh * 32 + qx) * 2;
  const float* O0 = Opart + (size_t)pid * 4096;
  const float* O1 = O0 + 4096;
  const int t = threadIdx.x;
  const int r_ = t >> 2, c4 = t & 3;
  const float l = Lpart[pid * 64 + r_] + Lpart[(pid + 1) * 64 + r_];
  const float inv = 1.f / l;
  short* dst = AOb + ((size_t)(b * TQ + qx * 64 + r_)) * DM + h * 64 + c4 * 16;
#pragma unroll
  for (int u = 0; u < 4; u++) {
    const int off = r_ * 64 + c4 * 16 + u * 4;
    const float4 v0 = *(const float4*)(O0 + off);
    const float4 v1 = *(const float4*)(O1 + off);
    short4 o;
    o.x = f2bf((v0.x + v1.x) * inv);
    o.y = f2bf((v0.y + v1.y) * inv);
    o.z = f2bf((v0.z + v1.z) * inv);
    o.w = f2bf((v0.w + v1.w) * inv);
    *(short4*)(dst + u * 4) = o;
  }
}

// ---------- expand k output: cache part from kc (exact), new part from Kb bf16 ----------
__global__ void k_expand_k(const float* __restrict__ kc, const short* __restrict__ Kb,
                           float* __restrict__ kF) {
  const size_t f4 = (size_t)blockIdx.x * 256 + threadIdx.x;
  const size_t e = f4 * 4;
  const int t = (int)((e >> 6) & 4095);
  float4 v;
  if (t < TCACHE) {
    const int dh = (int)(e & 63);
    const int bh = (int)(e >> 18);
    v = *(const float4*)(kc + ((size_t)(bh * TCACHE + t)) * DH + dh);
  } else {
    const short4 s = *(const short4*)(Kb + e);
    v.x = bf2f(s.x); v.y = bf2f(s.y); v.z = bf2f(s.z); v.w = bf2f(s.w);
  }
  *(float4*)(kF + e) = v;
}

// ---------- expand v output: cache part from vc, new part transposed from Vtb ----------
__global__ void k_expand_v(const float* __restrict__ vc, const short* __restrict__ Vtb,
                           float* __restrict__ vF) {
  __shared__ short tile[64 * 72];
  const int tt = (int)blockIdx.x, bh = (int)blockIdx.y;
  if (tt < 32) {
#pragma unroll
    for (int k2 = 0; k2 < 4; k2++) {
      const int f = threadIdx.x + k2 * 256;
      const int trow = f >> 4, dh4 = f & 15;
      const size_t si = ((size_t)(bh * TCACHE) + tt * 64 + trow) * DH + dh4 * 4;
      const size_t di = ((size_t)(bh * TKTOT) + tt * 64 + trow) * DH + dh4 * 4;
      *(float4*)(vF + di) = *(const float4*)(vc + si);
    }
  } else {
    const int t0 = tt * 64;
#pragma unroll
    for (int k2 = 0; k2 < 4; k2++) {
      const int f = threadIdx.x + k2 * 256;
      const int dh = f >> 4, tc4 = f & 15;
      const short4 s = *(const short4*)(Vtb + ((size_t)(bh * DH + dh)) * TKTOT + t0 + tc4 * 4);
      *(short4*)(&tile[dh * 72 + tc4 * 4]) = s;
    }
    __syncthreads();
#pragma unroll
    for (int k2 = 0; k2 < 4; k2++) {
      const int f = threadIdx.x + k2 * 256;
      const int trow = f >> 4, dh4 = f & 15;
      float4 v;
      v.x = bf2f(tile[(dh4 * 4 + 0) * 72 + trow]);
      v.y = bf2f(tile[(dh4 * 4 + 1) * 72 + trow]);
      v.z = bf2f(tile[(dh4 * 4 + 2) * 72 + trow]);
      v.w = bf2f(tile[(dh4 * 4 + 3) * 72 + trow]);
      *(float4*)(vF + ((size_t)(bh * TKTOT) + t0 + trow) * DH + dh4 * 4) = v;
    }
  }
}

// ---------- host ----------

extern "C" void kernel_launch(void* const* d_in, const int* in_sizes, int n_in,
                              void* d_out, int out_size, void* d_ws, size_t ws_size,
                              hipStream_t stream) {
  const float* x = (const float*)d_in[0];
  const float* kc = (const float*)d_in[1];
  const float* vc = (const float*)d_in[2];
  const float* Wq = (const float*)d_in[3];
  const float* bq = (const float*)d_in[4];
  const float* Wk = (const float*)d_in[5];
  const float* bk = (const float*)d_in[6];
  const float* Wv = (const float*)d_in[7];
  const float* bv = (const float*)d_in[8];
  const float* Wo = (const float*)d_in[9];
  const float* bo = (const float*)d_in[10];

  float* out = (float*)d_out;
  float* kF = out + (size_t)BB * TQ * DM;          // k output region (33.55 MB)
  float* vF = kF + (size_t)BB * NH * TKTOT * DH;   // v output region (33.55 MB)
  float* Opart = kF;  // attention O partials: 2048 x 4096 f32 = exact fit in k region
  float* Lpart = vF;  // l partials: 2048 x 64 f32 at start of v region

  char* ws = (char*)d_ws;
  short* xb = (short*)ws;   ws += (size_t)MROWS * DM * 2;
  short* Wt = (short*)ws;   ws += (size_t)4 * DM * DM * 2;
  short* Qb = (short*)ws;   ws += (size_t)BB * NH * TQ * DH * 2;
  short* Kb = (short*)ws;   ws += (size_t)BB * NH * TKTOT * DH * 2;
  short* Vtb = (short*)ws;  ws += (size_t)BB * NH * TKTOT * DH * 2;
  short* AOb = (short*)ws;  // total ws use: 64 MiB

  k_cvt_x<<<4096, 256, 0, stream>>>(x, xb);
  k_transpose_w<<<dim3(32, 32, 4), 256, 0, stream>>>(Wq, Wk, Wv, Wo, Wt);
  k_copy_kcache<<<4096, 256, 0, stream>>>(kc, Kb);
  k_copy_vcache<<<dim3(32, 32), 256, 0, stream>>>(vc, Vtb);
  k_gemm<<<dim3(DM / 128, MROWS / 64, 3), 256, 0, stream>>>(
      xb, Wt, bq, bk, bv, 1, nullptr, Qb, Kb, Vtb);
  k_attn<<<dim3(2, 32, 32), 256, 0, stream>>>(Qb, Kb, Vtb, Opart, Lpart);
  k_reduce<<<dim3(32, 32), 256, 0, stream>>>(Opart, Lpart, AOb);
  k_expand_k<<<8192, 256, 0, stream>>>(kc, Kb, kF);
  k_expand_v<<<dim3(64, 32), 256, 0, stream>>>(vc, Vtb, vF);
  k_gemm<<<dim3(DM / 128, MROWS / 64, 1), 256, 0, stream>>>(
      AOb, Wt + (size_t)3 * DM * DM, bo, bo, bo, 0, out, nullptr, nullptr, nullptr);
}

// Round 2
// 348.534 us; speedup vs baseline: 1.0660x; 1.0295x over previous
//
#include <hip/hip_runtime.h>
#include <hip/hip_bf16.h>
#include <cstdint>
#include <cstddef>

#define DM 1024
#define NH 16
#define DH 64
#define BB 2
#define TQ 2048
#define TCACHE 2048
#define TKTOT 4096
#define MROWS 4096

typedef __attribute__((ext_vector_type(8))) short bf16x8;
typedef __attribute__((ext_vector_type(4))) short bf16x4;
typedef __attribute__((ext_vector_type(4))) float f32x4;
typedef __attribute__((ext_vector_type(16))) float f32x16;

__device__ __forceinline__ short f2bf(float f) {
  union { float f; unsigned u; } v; v.f = f;
  unsigned r = v.u + 0x7fffu + ((v.u >> 16) & 1u);
  return (short)(r >> 16);
}

__device__ __forceinline__ float bf2f(short s) {
  union { unsigned u; float f; } v;
  v.u = ((unsigned)(unsigned short)s) << 16;
  return v.f;
}

__device__ __forceinline__ float exp2fast(float x) {
#if __has_builtin(__builtin_amdgcn_exp2f)
  return __builtin_amdgcn_exp2f(x);
#else
  return exp2f(x);
#endif
}

// pack two f32 -> two bf16 in one dword (RNE)
__device__ __forceinline__ unsigned pk2(float a, float b) {
#if __has_builtin(__builtin_amdgcn_cvt_pk_bf16_f32)
  typedef __bf16 bf2 __attribute__((ext_vector_type(2)));
  union { bf2 v; unsigned u; } cv;
  cv.v = __builtin_amdgcn_cvt_pk_bf16_f32(a, b);
  return cv.u;
#else
  return (unsigned)(unsigned short)f2bf(a) | ((unsigned)(unsigned short)f2bf(b) << 16);
#endif
}

// v_permlane32_swap_b32: a' = {a.lo, b.lo}, b' = {a.hi, b.hi} (lane halves)
__device__ __forceinline__ void plswap(unsigned& a, unsigned& b) {
  asm volatile("v_permlane32_swap_b32 %0, %1" : "+v"(a), "+v"(b));
}

// async global->LDS, 16B/lane. LDS dest must be wave-uniform base + lane*16;
// swizzle goes on the GLOBAL address only (m104/m108).
__device__ __forceinline__ void gld_lds16(const short* g, short* l) {
  __builtin_amdgcn_global_load_lds(
      (const __attribute__((address_space(1))) void*)((uintptr_t)g),
      (__attribute__((address_space(3))) void*)((uintptr_t)l), 16, 0, 0);
}

// ---------- prep kernels ----------

__global__ void k_cvt_x(const float* __restrict__ x, short* __restrict__ xb) {
  const size_t i = (size_t)blockIdx.x * 256 + threadIdx.x;
  const float4 v = ((const float4*)x)[i];
  short4 o;
  o.x = f2bf(v.x); o.y = f2bf(v.y); o.z = f2bf(v.z); o.w = f2bf(v.w);
  ((short4*)xb)[i] = o;
}

// W [K][N] f32 -> Wt bf16 [N][K], 4 weights via blockIdx.z
__global__ void k_transpose_w(const float* __restrict__ W0, const float* __restrict__ W1,
                              const float* __restrict__ W2, const float* __restrict__ W3,
                              short* __restrict__ Wt) {
  __shared__ short tile[32][33];
  const float* W = (blockIdx.z == 0) ? W0 : (blockIdx.z == 1) ? W1 : (blockIdx.z == 2) ? W2 : W3;
  short* dst = Wt + (size_t)blockIdx.z * DM * DM;
  const int k0 = blockIdx.y * 32, n0 = blockIdx.x * 32;
  const int tx = threadIdx.x & 31, ty = threadIdx.x >> 5;
#pragma unroll
  for (int r = 0; r < 4; r++) {
    const int k = ty + r * 8;
    tile[k][tx] = f2bf(W[(size_t)(k0 + k) * DM + n0 + tx]);
  }
  __syncthreads();
#pragma unroll
  for (int r = 0; r < 4; r++) {
    const int n = ty + r * 8;
    dst[(size_t)(n0 + n) * DM + k0 + tx] = tile[tx][n];
  }
}

// k_cache f32 -> bf16 Kb cache part only
__global__ void k_copy_kcache(const float* __restrict__ kc, short* __restrict__ Kb) {
  const size_t i = (size_t)blockIdx.x * 256 + threadIdx.x;
  const float4 v = ((const float4*)kc)[i];
  const size_t e = i * 4;
  const int dh = (int)(e & 63);
  const int t = (int)((e >> 6) & 2047);
  const int bh = (int)(e >> 17);
  short4 o;
  o.x = f2bf(v.x); o.y = f2bf(v.y); o.z = f2bf(v.z); o.w = f2bf(v.w);
  *(short4*)(Kb + ((size_t)bh * TKTOT + t) * DH + dh) = o;
}

// v_cache f32 -> transposed bf16 Vt[b,h,dh,t] cache part only
__global__ void k_copy_vcache(const float* __restrict__ vc, short* __restrict__ Vtb) {
  __shared__ short tile[64][65];  // [dh][t]
  const int bh = blockIdx.y;
  const int t0 = blockIdx.x * 64;
  const int tx = threadIdx.x & 15, ty = threadIdx.x >> 4;
  const float* src = vc + ((size_t)bh * TCACHE + t0) * DH;
#pragma unroll
  for (int r = 0; r < 4; r++) {
    const int t = ty + r * 16;
    const float4 v = *(const float4*)(src + (size_t)t * DH + tx * 4);
    tile[tx * 4 + 0][t] = f2bf(v.x);
    tile[tx * 4 + 1][t] = f2bf(v.y);
    tile[tx * 4 + 2][t] = f2bf(v.z);
    tile[tx * 4 + 3][t] = f2bf(v.w);
  }
  __syncthreads();
  short* vt = Vtb + (size_t)bh * DH * TKTOT + t0;
#pragma unroll
  for (int r = 0; r < 4; r++) {
    const int dh = ty + r * 16;
    short4 o;
    o.x = tile[dh][tx * 4 + 0];
    o.y = tile[dh][tx * 4 + 1];
    o.z = tile[dh][tx * 4 + 2];
    o.w = tile[dh][tx * 4 + 3];
    *(short4*)(vt + (size_t)dh * TKTOT + tx * 4) = o;
  }
}

// ---------- GEMM: C[M,N] = A[M,K] * Bt[N,K]^T + bias ----------
// 64x128 tile (M x N), BK=32, 256 threads (4 waves, 32x64 each).
// Double-buffered staging: next K-step's global_load_lds flies during compute.
__global__ __launch_bounds__(256) void k_gemm(
    const short* __restrict__ A, const short* __restrict__ Bt,
    const float* __restrict__ b0, const float* __restrict__ b1, const float* __restrict__ b2,
    const int is_qkv, float* __restrict__ fdst,
    short* __restrict__ Qb, short* __restrict__ Kb, short* __restrict__ Vtb) {
  const int z = is_qkv ? (int)blockIdx.z : 3;
  const short* Bz = Bt + (is_qkv ? (size_t)z * DM * DM : 0);
  const float* bias = (z == 0 || z == 3) ? b0 : (z == 1 ? b1 : b2);

  __shared__ short sA[2][64 * 32];   // 2 x 4KB
  __shared__ short sB[2][128 * 32];  // 2 x 8KB

  const int m0 = blockIdx.y * 64;
  const int n0 = blockIdx.x * 128;
  const int tid = threadIdx.x;
  const int wv = tid >> 6;
  const int lane = tid & 63;
  const int quad = lane >> 4;
  const int l16 = lane & 15;
  const int wm = (wv >> 1) * 32;
  const int wn = (wv & 1) * 64;

  const f32x4 zero = {0.f, 0.f, 0.f, 0.f};
  f32x4 acc[2][4];
#pragma unroll
  for (int i = 0; i < 2; i++)
#pragma unroll
    for (int j = 0; j < 4; j++) acc[i][j] = zero;

  // kt-invariant fragment read offsets (bytes): row*64 + swizzled-chunk*16
  const int sw = (quad ^ ((l16 >> 1) & 3)) << 4;
  const int afo = (wm + l16) * 64 + sw;
  const int bfo = (wn + l16) * 64 + sw;

#define STAGEG(k0_, b_)                                                        \
  do {                                                                         \
    {                                                                          \
      const int c = tid;                                                       \
      const int row = c >> 2, cs = c & 3;                                      \
      const int gc = cs ^ ((row >> 1) & 3);                                    \
      gld_lds16(A + (size_t)(m0 + row) * DM + (k0_) + gc * 8, &sA[b_][c * 8]); \
    }                                                                          \
    _Pragma("unroll") for (int s = 0; s < 2; s++) {                            \
      const int c = tid + s * 256;                                             \
      const int row = c >> 2, cs = c & 3;                                      \
      const int gc = cs ^ ((row >> 1) & 3);                                    \
      gld_lds16(Bz + (size_t)(n0 + row) * DM + (k0_) + gc * 8, &sB[b_][c * 8]); \
    }                                                                          \
  } while (0)

  STAGEG(0, 0);
  __syncthreads();
  int buf = 0;
  for (int k0 = 0; k0 < DM; k0 += 32) {
    if (k0 + 32 < DM) STAGEG(k0 + 32, buf ^ 1);
    const char* Ab = (const char*)&sA[0][0] + buf * 4096;
    const char* Bb = (const char*)&sB[0][0] + buf * 8192;
    bf16x8 af[2], bfv[4];
#pragma unroll
    for (int i = 0; i < 2; i++) af[i] = *(const bf16x8*)(Ab + afo + i * 1024);
#pragma unroll
    for (int j = 0; j < 4; j++) bfv[j] = *(const bf16x8*)(Bb + bfo + j * 1024);
#pragma unroll
    for (int i = 0; i < 2; i++)
#pragma unroll
      for (int j = 0; j < 4; j++)
        acc[i][j] = __builtin_amdgcn_mfma_f32_16x16x32_bf16(af[i], bfv[j], acc[i][j], 0, 0, 0);
    __syncthreads();
    buf ^= 1;
  }
#undef STAGEG

#pragma unroll
  for (int i = 0; i < 2; i++) {
#pragma unroll
    for (int j = 0; j < 4; j++) {
      const int gn = n0 + wn + j * 16 + l16;
      const float bb = bias[gn];
#pragma unroll
      for (int r = 0; r < 4; r++) {
        const int gm = m0 + wm + i * 16 + quad * 4 + r;
        const float v = acc[i][j][r] + bb;
        if (z == 3) {
          fdst[(size_t)gm * DM + gn] = v;
        } else {
          const int b_ = gm >> 11, t = gm & 2047;
          const int h_ = gn >> 6, dh = gn & 63;
          if (z == 0) {
            // fold softmax scale AND log2(e): 0.125 * 1.4426950409
            Qb[(((size_t)(b_ * NH + h_)) * TQ + t) * DH + dh] = f2bf(v * 0.18033688011f);
          } else if (z == 1) {
            Kb[(((size_t)(b_ * NH + h_)) * TKTOT + TCACHE + t) * DH + dh] = f2bf(v);
          } else {
            Vtb[(((size_t)(b_ * NH + h_)) * DH + dh) * TKTOT + TCACHE + t] = f2bf(v);
          }
        }
      }
    }
  }
}

// ---------- flash attention v3: 32x32x16 MFMA, QBLK=128, in-register P ----------
// grid (2 splits, 16 q-blocks, 32 bh); 128 q rows/block; wave w owns rows [q0+32w, +32).
// Sacc = K*Q^T via 32x32x16 (col=lane&31=q, row=key reg-indexed); softmax in-reg;
// P redistributed to PV A-operand with cvt_pk + v_permlane32_swap (T12) -- zero
// LDS for P. V consumed as B-operand from Vt[dh][t] LDS (contiguous 16B/lane).
// LDS traffic per unit work ~2.5x lower than the 16x16 version (the measured
// bottleneck: LDS pipe ~940cyc/tile vs MFMA ~130).
__global__ __launch_bounds__(256, 3) void k_attn(const short* __restrict__ Qb,
                                                 const short* __restrict__ Kb,
                                                 const short* __restrict__ Vtb,
                                                 float* __restrict__ Opart,
                                                 float* __restrict__ Lpart) {
  __shared__ short sK[2][64 * 64];  // [key][dh], chunk^(row&7) swizzle, 2x8KB
  __shared__ short sV[2][64 * 64];  // [dh][key], chunk^(row&7) swizzle, 2x8KB

  const int split = (int)blockIdx.x;
  const int qx = 15 - (int)blockIdx.y;  // longest blocks first
  const int bh = (int)blockIdx.z;
  const int q0 = qx * 128;
  const int tid = threadIdx.x;
  const int wq = tid >> 6;
  const int lane = tid & 63;
  const int l32 = lane & 31;
  const int h = lane >> 5;

  const int nkt = 2 * qx + 34;  // total key tiles for this q-block
  const int halfn = nkt >> 1;
  const int kt0 = split ? halfn : 0;
  const int kt1 = split ? nkt : halfn;

  const short* Kg = Kb + (size_t)bh * TKTOT * DH;
  const short* Vtg = Vtb + (size_t)bh * DH * TKTOT;

  // staging source pointers (per-thread, kt-invariant part)
  const int c0 = tid, c1 = tid + 256;
  const int r0 = c0 >> 3, g0 = ((c0 & 7) ^ (r0 & 7)) * 8;
  const int r1 = c1 >> 3, g1 = ((c1 & 7) ^ (r1 & 7)) * 8;
  const short* Kst0 = Kg + (size_t)r0 * DH + g0;
  const short* Kst1 = Kg + (size_t)r1 * DH + g1;
  const short* Vst0 = Vtg + (size_t)r0 * TKTOT + g0;
  const short* Vst1 = Vtg + (size_t)r1 * TKTOT + g1;

  // Q fragments straight from global: B-operand, lane holds q=l32, k=8h+i
  const short* Qrow = Qb + ((size_t)bh * TQ + q0 + wq * 32 + l32) * DH;
  bf16x8 qf[4];
#pragma unroll
  for (int s = 0; s < 4; s++) qf[s] = *(const bf16x8*)(Qrow + s * 16 + h * 8);

  // kt-invariant LDS read offsets: row = (32*blk + l32), chunk c=2*ks+h, swz c^(row&7)
  const char* sKc = (const char*)&sK[0][0];
  const char* sVc = (const char*)&sV[0][0];
  const int rx7 = l32 & 7;
  const int base0 = l32 * 128;
  const int base1 = base0 + 4096;
  int co[4];
#pragma unroll
  for (int ks = 0; ks < 4; ks++) co[ks] = ((2 * ks + h) ^ rx7) << 4;

  f32x16 of0 = {0, 0, 0, 0, 0, 0, 0, 0, 0, 0, 0, 0, 0, 0, 0, 0};
  f32x16 of1 = {0, 0, 0, 0, 0, 0, 0, 0, 0, 0, 0, 0, 0, 0, 0, 0};
  float la = 0.f, lb = 0.f, lc = 0.f, ld = 0.f;

#define STAGE(t_, b_)                               \
  do {                                              \
    const size_t koff = (size_t)(t_) * 64 * DH;     \
    const size_t voff = (size_t)(t_) * 64;          \
    short* dK = &sK[b_][0];                         \
    short* dV = &sV[b_][0];                         \
    gld_lds16(Kst0 + koff, dK + c0 * 8);            \
    gld_lds16(Kst1 + koff, dK + c1 * 8);            \
    gld_lds16(Vst0 + voff, dV + c0 * 8);            \
    gld_lds16(Vst1 + voff, dV + c1 * 8);            \
  } while (0)

  STAGE(kt0, 0);
  __syncthreads();
  int buf = 0;

  for (int t = kt0; t < kt1; t++) {
    if (t + 1 < kt1) STAGE(t + 1, buf ^ 1);
    const char* kb_ = sKc + buf * 8192;
    const char* vb_ = sVc + buf * 8192;

    // Sacc = K * Q^T : col(lane&31)=q, row(reg)=key = (r&3)+8*(r>>2)+4h (+32 for blk1)
    f32x16 sacc0 = {0, 0, 0, 0, 0, 0, 0, 0, 0, 0, 0, 0, 0, 0, 0, 0};
    f32x16 sacc1 = {0, 0, 0, 0, 0, 0, 0, 0, 0, 0, 0, 0, 0, 0, 0, 0};
    __builtin_amdgcn_s_setprio(1);
#pragma unroll
    for (int ks = 0; ks < 4; ks++) {
      const bf16x8 kf0 = *(const bf16x8*)(kb_ + base0 + co[ks]);
      const bf16x8 kf1 = *(const bf16x8*)(kb_ + base1 + co[ks]);
      sacc0 = __builtin_amdgcn_mfma_f32_32x32x16_bf16(kf0, qf[ks], sacc0, 0, 0, 0);
      sacc1 = __builtin_amdgcn_mfma_f32_32x32x16_bf16(kf1, qf[ks], sacc1, 0, 0, 0);
    }
    __builtin_amdgcn_s_setprio(0);

    if (t >= nkt - 2) {  // diagonal spans 2 tiles at QBLK=128
      const int qgl = q0 + wq * 32 + l32 + TCACHE;
      const int kb0 = t * 64 + 4 * h;
#pragma unroll
      for (int r = 0; r < 16; r++) {
        const int key = kb0 + (r & 3) + 8 * (r >> 2);
        if (key > qgl) sacc0[r] = -1e30f;
        if (key + 32 > qgl) sacc1[r] = -1e30f;
      }
    }
#pragma unroll
    for (int r = 0; r < 16; r++) {
      const float e0 = exp2fast(sacc0[r]);
      const float e1 = exp2fast(sacc1[r]);
      sacc0[r] = e0;
      sacc1[r] = e1;
      if ((r & 3) == 0) la += e0 + e1;
      else if ((r & 3) == 1) lb += e0 + e1;
      else if ((r & 3) == 2) lc += e0 + e1;
      else ld += e0 + e1;
    }

    // pack + lane-half swap -> PV A-operand: row(lane&31)=q, k=8h+i per kstep
    bf16x8 pa[4];
#pragma unroll
    for (int s = 0; s < 4; s++) {
      const int o = (s & 1) * 8;
      unsigned w0, w1, w2, w3;
      if (s < 2) {
        w0 = pk2(sacc0[o + 0], sacc0[o + 1]);
        w1 = pk2(sacc0[o + 2], sacc0[o + 3]);
        w2 = pk2(sacc0[o + 4], sacc0[o + 5]);
        w3 = pk2(sacc0[o + 6], sacc0[o + 7]);
      } else {
        w0 = pk2(sacc1[o + 0], sacc1[o + 1]);
        w1 = pk2(sacc1[o + 2], sacc1[o + 3]);
        w2 = pk2(sacc1[o + 4], sacc1[o + 5]);
        w3 = pk2(sacc1[o + 6], sacc1[o + 7]);
      }
      plswap(w0, w2);  // w0={lo,lo}, w2={hi,hi}
      plswap(w1, w3);
      union { unsigned u[4]; bf16x8 v; } pu;
      pu.u[0] = w0; pu.u[1] = w1; pu.u[2] = w2; pu.u[3] = w3;
      pa[s] = pu.v;
    }

    // O[q][dh] += P * V : B=V[k][dh] from Vt LDS (lane: dh=32b+l32, t=16ks+8h..+7)
    __builtin_amdgcn_s_setprio(1);
#pragma unroll
    for (int ks = 0; ks < 4; ks++) {
      const bf16x8 vf0 = *(const bf16x8*)(vb_ + base0 + co[ks]);
      const bf16x8 vf1 = *(const bf16x8*)(vb_ + base1 + co[ks]);
      of0 = __builtin_amdgcn_mfma_f32_32x32x16_bf16(pa[ks], vf0, of0, 0, 0, 0);
      of1 = __builtin_amdgcn_mfma_f32_32x32x16_bf16(pa[ks], vf1, of1, 0, 0, 0);
    }
    __builtin_amdgcn_s_setprio(0);
    __syncthreads();
    buf ^= 1;
  }
#undef STAGE

  // write partials: O[128q][64dh] f32 + l[128] f32
  const int pid = (bh * 16 + qx) * 2 + split;
  float* Op = Opart + (size_t)pid * 8192;
#pragma unroll
  for (int r = 0; r < 16; r++) {
    const int ql = wq * 32 + (r & 3) + 8 * (r >> 2) + 4 * h;
    Op[ql * 64 + l32] = of0[r];
    Op[ql * 64 + 32 + l32] = of1[r];
  }
  const float l_lane = (la + lb) + (lc + ld);
  const float l_tot = l_lane + __shfl_xor(l_lane, 32);
  if (h == 0) Lpart[(size_t)pid * 128 + wq * 32 + l32] = l_tot;
}

// ---------- reduce: combine 2 splits, normalize, write AOb bf16 ----------
__global__ __launch_bounds__(256) void k_reduce(const float* __restrict__ Opart,
                                                const float* __restrict__ Lpart,
                                                short* __restrict__ AOb) {
  const int qx = (int)blockIdx.x, bh = (int)blockIdx.y;  // qx: 64-row blocks
  const int b = bh >> 4, hd = bh & 15;
  const int qxb = qx >> 1, hf = qx & 1;
  const int pid = (bh * 16 + qxb) * 2;
  const float* O0 = Opart + (size_t)pid * 8192 + hf * 4096;
  const float* O1 = O0 + 8192;
  const int t = threadIdx.x;
  const int r_ = t >> 2, c4 = t & 3;
  const float l = Lpart[(size_t)pid * 128 + hf * 64 + r_] +
                  Lpart[(size_t)(pid + 1) * 128 + hf * 64 + r_];
  const float inv = 1.f / l;
  short* dst = AOb + ((size_t)(b * TQ + qx * 64 + r_)) * DM + hd * 64 + c4 * 16;
#pragma unroll
  for (int u = 0; u < 4; u++) {
    const int off = r_ * 64 + c4 * 16 + u * 4;
    const float4 v0 = *(const float4*)(O0 + off);
    const float4 v1 = *(const float4*)(O1 + off);
    short4 o;
    o.x = f2bf((v0.x + v1.x) * inv);
    o.y = f2bf((v0.y + v1.y) * inv);
    o.z = f2bf((v0.z + v1.z) * inv);
    o.w = f2bf((v0.w + v1.w) * inv);
    *(short4*)(dst + u * 4) = o;
  }
}

// ---------- expand k output: cache part from kc (exact), new part from Kb bf16 ----------
__global__ void k_expand_k(const float* __restrict__ kc, const short* __restrict__ Kb,
                           float* __restrict__ kF) {
  const size_t f4 = (size_t)blockIdx.x * 256 + threadIdx.x;
  const size_t e = f4 * 4;
  const int t = (int)((e >> 6) & 4095);
  float4 v;
  if (t < TCACHE) {
    const int dh = (int)(e & 63);
    const int bh = (int)(e >> 18);
    v = *(const float4*)(kc + ((size_t)(bh * TCACHE + t)) * DH + dh);
  } else {
    const short4 s = *(const short4*)(Kb + e);
    v.x = bf2f(s.x); v.y = bf2f(s.y); v.z = bf2f(s.z); v.w = bf2f(s.w);
  }
  *(float4*)(kF + e) = v;
}

// ---------- expand v output: cache part from vc, new part transposed from Vtb ----------
__global__ void k_expand_v(const float* __restrict__ vc, const short* __restrict__ Vtb,
                           float* __restrict__ vF) {
  __shared__ short tile[64 * 72];
  const int tt = (int)blockIdx.x, bh = (int)blockIdx.y;
  if (tt < 32) {
#pragma unroll
    for (int k2 = 0; k2 < 4; k2++) {
      const int f = threadIdx.x + k2 * 256;
      const int trow = f >> 4, dh4 = f & 15;
      const size_t si = ((size_t)(bh * TCACHE) + tt * 64 + trow) * DH + dh4 * 4;
      const size_t di = ((size_t)(bh * TKTOT) + tt * 64 + trow) * DH + dh4 * 4;
      *(float4*)(vF + di) = *(const float4*)(vc + si);
    }
  } else {
    const int t0 = tt * 64;
#pragma unroll
    for (int k2 = 0; k2 < 4; k2++) {
      const int f = threadIdx.x + k2 * 256;
      const int dh = f >> 4, tc4 = f & 15;
      const short4 s = *(const short4*)(Vtb + ((size_t)(bh * DH + dh)) * TKTOT + t0 + tc4 * 4);
      *(short4*)(&tile[dh * 72 + tc4 * 4]) = s;
    }
    __syncthreads();
#pragma unroll
    for (int k2 = 0; k2 < 4; k2++) {
      const int f = threadIdx.x + k2 * 256;
      const int trow = f >> 4, dh4 = f & 15;
      float4 v;
      v.x = bf2f(tile[(dh4 * 4 + 0) * 72 + trow]);
      v.y = bf2f(tile[(dh4 * 4 + 1) * 72 + trow]);
      v.z = bf2f(tile[(dh4 * 4 + 2) * 72 + trow]);
      v.w = bf2f(tile[(dh4 * 4 + 3) * 72 + trow]);
      *(float4*)(vF + ((size_t)(bh * TKTOT) + t0 + trow) * DH + dh4 * 4) = v;
    }
  }
}

// ---------- host ----------

extern "C" void kernel_launch(void* const* d_in, const int* in_sizes, int n_in,
                              void* d_out, int out_size, void* d_ws, size_t ws_size,
                              hipStream_t stream) {
  const float* x = (const float*)d_in[0];
  const float* kc = (const float*)d_in[1];
  const float* vc = (const float*)d_in[2];
  const float* Wq = (const float*)d_in[3];
  const float* bq = (const float*)d_in[4];
  const float* Wk = (const float*)d_in[5];
  const float* bk = (const float*)d_in[6];
  const float* Wv = (const float*)d_in[7];
  const float* bv = (const float*)d_in[8];
  const float* Wo = (const float*)d_in[9];
  const float* bo = (const float*)d_in[10];

  float* out = (float*)d_out;
  float* kF = out + (size_t)BB * TQ * DM;          // k output region (33.55 MB)
  float* vF = kF + (size_t)BB * NH * TKTOT * DH;   // v output region (33.55 MB)
  float* Opart = kF;  // attention O partials: 1024 x 8192 f32 = exact fit in k region
  float* Lpart = vF;  // l partials: 1024 x 128 f32 at start of v region

  char* ws = (char*)d_ws;
  short* xb = (short*)ws;   ws += (size_t)MROWS * DM * 2;
  short* Wt = (short*)ws;   ws += (size_t)4 * DM * DM * 2;
  short* Qb = (short*)ws;   ws += (size_t)BB * NH * TQ * DH * 2;
  short* Kb = (short*)ws;   ws += (size_t)BB * NH * TKTOT * DH * 2;
  short* Vtb = (short*)ws;  ws += (size_t)BB * NH * TKTOT * DH * 2;
  short* AOb = (short*)ws;  // total ws use: 64 MiB

  k_cvt_x<<<4096, 256, 0, stream>>>(x, xb);
  k_transpose_w<<<dim3(32, 32, 4), 256, 0, stream>>>(Wq, Wk, Wv, Wo, Wt);
  k_copy_kcache<<<4096, 256, 0, stream>>>(kc, Kb);
  k_copy_vcache<<<dim3(32, 32), 256, 0, stream>>>(vc, Vtb);
  k_gemm<<<dim3(DM / 128, MROWS / 64, 3), 256, 0, stream>>>(
      xb, Wt, bq, bk, bv, 1, nullptr, Qb, Kb, Vtb);
  k_attn<<<dim3(2, 16, 32), 256, 0, stream>>>(Qb, Kb, Vtb, Opart, Lpart);
  k_reduce<<<dim3(32, 32), 256, 0, stream>>>(Opart, Lpart, AOb);
  k_expand_k<<<8192, 256, 0, stream>>>(kc, Kb, kF);
  k_expand_v<<<dim3(64, 32), 256, 0, stream>>>(vc, Vtb, vF);
  k_gemm<<<dim3(DM / 128, MROWS / 64, 1), 256, 0, stream>>>(
      AOb, Wt + (size_t)3 * DM * DM, bo, bo, bo, 0, out, nullptr, nullptr, nullptr);
}

// Round 3
// 341.626 us; speedup vs baseline: 1.0876x; 1.0202x over previous
//
#include <hip/hip_runtime.h>
#include <hip/hip_bf16.h>
#include <cstdint>
#include <cstddef>

#define DM 1024
#define NH 16
#define DH 64
#define BB 2
#define TQ 2048
#define TCACHE 2048
#define TKTOT 4096
#define MROWS 4096

typedef __attribute__((ext_vector_type(8))) short bf16x8;
typedef __attribute__((ext_vector_type(4))) short bf16x4;
typedef __attribute__((ext_vector_type(4))) float f32x4;
typedef __attribute__((ext_vector_type(16))) float f32x16;

__device__ __forceinline__ short f2bf(float f) {
  union { float f; unsigned u; } v; v.f = f;
  unsigned r = v.u + 0x7fffu + ((v.u >> 16) & 1u);
  return (short)(r >> 16);
}

__device__ __forceinline__ float bf2f(short s) {
  union { unsigned u; float f; } v;
  v.u = ((unsigned)(unsigned short)s) << 16;
  return v.f;
}

__device__ __forceinline__ float exp2fast(float x) {
#if __has_builtin(__builtin_amdgcn_exp2f)
  return __builtin_amdgcn_exp2f(x);
#else
  return exp2f(x);
#endif
}

// pack two f32 -> two bf16 in one dword (RNE)
__device__ __forceinline__ unsigned pk2(float a, float b) {
#if __has_builtin(__builtin_amdgcn_cvt_pk_bf16_f32)
  typedef __bf16 bf2 __attribute__((ext_vector_type(2)));
  union { bf2 v; unsigned u; } cv;
  cv.v = __builtin_amdgcn_cvt_pk_bf16_f32(a, b);
  return cv.u;
#else
  return (unsigned)(unsigned short)f2bf(a) | ((unsigned)(unsigned short)f2bf(b) << 16);
#endif
}

// v_permlane32_swap_b32: a' = {a.lo, b.lo}, b' = {a.hi, b.hi} (lane halves)
__device__ __forceinline__ void plswap(unsigned& a, unsigned& b) {
  asm volatile("v_permlane32_swap_b32 %0, %1" : "+v"(a), "+v"(b));
}

// async global->LDS, 16B/lane. LDS dest must be wave-uniform base + lane*16;
// swizzle goes on the GLOBAL address only (m104/m108).
__device__ __forceinline__ void gld_lds16(const short* g, short* l) {
  __builtin_amdgcn_global_load_lds(
      (const __attribute__((address_space(1))) void*)((uintptr_t)g),
      (__attribute__((address_space(3))) void*)((uintptr_t)l), 16, 0, 0);
}

// ---------- prep kernels ----------

__global__ void k_cvt_x(const float* __restrict__ x, short* __restrict__ xb) {
  const size_t i = (size_t)blockIdx.x * 256 + threadIdx.x;
  const float4 v = ((const float4*)x)[i];
  short4 o;
  o.x = f2bf(v.x); o.y = f2bf(v.y); o.z = f2bf(v.z); o.w = f2bf(v.w);
  ((short4*)xb)[i] = o;
}

// W [K][N] f32 -> Wt bf16 [N][K], 4 weights via blockIdx.z
__global__ void k_transpose_w(const float* __restrict__ W0, const float* __restrict__ W1,
                              const float* __restrict__ W2, const float* __restrict__ W3,
                              short* __restrict__ Wt) {
  __shared__ short tile[32][33];
  const float* W = (blockIdx.z == 0) ? W0 : (blockIdx.z == 1) ? W1 : (blockIdx.z == 2) ? W2 : W3;
  short* dst = Wt + (size_t)blockIdx.z * DM * DM;
  const int k0 = blockIdx.y * 32, n0 = blockIdx.x * 32;
  const int tx = threadIdx.x & 31, ty = threadIdx.x >> 5;
#pragma unroll
  for (int r = 0; r < 4; r++) {
    const int k = ty + r * 8;
    tile[k][tx] = f2bf(W[(size_t)(k0 + k) * DM + n0 + tx]);
  }
  __syncthreads();
#pragma unroll
  for (int r = 0; r < 4; r++) {
    const int n = ty + r * 8;
    dst[(size_t)(n0 + n) * DM + k0 + tx] = tile[tx][n];
  }
}

// k_cache f32 -> bf16 Kb cache part only
__global__ void k_copy_kcache(const float* __restrict__ kc, short* __restrict__ Kb) {
  const size_t i = (size_t)blockIdx.x * 256 + threadIdx.x;
  const float4 v = ((const float4*)kc)[i];
  const size_t e = i * 4;
  const int dh = (int)(e & 63);
  const int t = (int)((e >> 6) & 2047);
  const int bh = (int)(e >> 17);
  short4 o;
  o.x = f2bf(v.x); o.y = f2bf(v.y); o.z = f2bf(v.z); o.w = f2bf(v.w);
  *(short4*)(Kb + ((size_t)bh * TKTOT + t) * DH + dh) = o;
}

// v_cache f32 -> transposed bf16 Vt[b,h,dh,t] cache part only
__global__ void k_copy_vcache(const float* __restrict__ vc, short* __restrict__ Vtb) {
  __shared__ short tile[64][65];  // [dh][t]
  const int bh = blockIdx.y;
  const int t0 = blockIdx.x * 64;
  const int tx = threadIdx.x & 15, ty = threadIdx.x >> 4;
  const float* src = vc + ((size_t)bh * TCACHE + t0) * DH;
#pragma unroll
  for (int r = 0; r < 4; r++) {
    const int t = ty + r * 16;
    const float4 v = *(const float4*)(src + (size_t)t * DH + tx * 4);
    tile[tx * 4 + 0][t] = f2bf(v.x);
    tile[tx * 4 + 1][t] = f2bf(v.y);
    tile[tx * 4 + 2][t] = f2bf(v.z);
    tile[tx * 4 + 3][t] = f2bf(v.w);
  }
  __syncthreads();
  short* vt = Vtb + (size_t)bh * DH * TKTOT + t0;
#pragma unroll
  for (int r = 0; r < 4; r++) {
    const int dh = ty + r * 16;
    short4 o;
    o.x = tile[dh][tx * 4 + 0];
    o.y = tile[dh][tx * 4 + 1];
    o.z = tile[dh][tx * 4 + 2];
    o.w = tile[dh][tx * 4 + 3];
    *(short4*)(vt + (size_t)dh * TKTOT + tx * 4) = o;
  }
}

// ---------- GEMM: C[M,N] = A[M,K] * Bt[N,K]^T + bias ----------
// 128x128 tile (m93/m97 geometry), BK=32, 256 threads (4 waves, 64x64 each),
// double-buffered global_load_lds staging. 16 MFMA : 8 ds_read_b128 per
// wave-step -- 2x the MFMA density of the old 64x128 tile.
__global__ __launch_bounds__(256) void k_gemm(
    const short* __restrict__ A, const short* __restrict__ Bt,
    const float* __restrict__ b0, const float* __restrict__ b1, const float* __restrict__ b2,
    const int is_qkv, float* __restrict__ fdst,
    short* __restrict__ Qb, short* __restrict__ Kb, short* __restrict__ Vtb) {
  const int z = is_qkv ? (int)blockIdx.z : 3;
  const short* Bz = Bt + (is_qkv ? (size_t)z * DM * DM : 0);
  const float* bias = (z == 0 || z == 3) ? b0 : (z == 1 ? b1 : b2);

  __shared__ short sA[2][128 * 32];  // 2 x 8KB
  __shared__ short sB[2][128 * 32];  // 2 x 8KB

  const int m0 = blockIdx.y * 128;
  const int n0 = blockIdx.x * 128;
  const int tid = threadIdx.x;
  const int wv = tid >> 6;
  const int lane = tid & 63;
  const int quad = lane >> 4;
  const int l16 = lane & 15;
  const int wm = (wv >> 1) * 64;
  const int wn = (wv & 1) * 64;

  const f32x4 zero = {0.f, 0.f, 0.f, 0.f};
  f32x4 acc[4][4];
#pragma unroll
  for (int i = 0; i < 4; i++)
#pragma unroll
    for (int j = 0; j < 4; j++) acc[i][j] = zero;

  // kt-invariant fragment read offsets (bytes): row*64 + swizzled-chunk*16
  // ((wm+i*16+l16)>>1)&3 == (l16>>1)&3 because wm+i*16 is 16-aligned.
  const int sw = (quad ^ ((l16 >> 1) & 3)) << 4;
  const int afo = (wm + l16) * 64 + sw;
  const int bfo = (wn + l16) * 64 + sw;

#define STAGEG(k0_, b_)                                                         \
  do {                                                                          \
    _Pragma("unroll") for (int s = 0; s < 2; s++) {                             \
      const int c = tid + s * 256;                                              \
      const int row = c >> 2, cs = c & 3;                                       \
      const int gc = cs ^ ((row >> 1) & 3);                                     \
      gld_lds16(A + (size_t)(m0 + row) * DM + (k0_) + gc * 8, &sA[b_][c * 8]);  \
      gld_lds16(Bz + (size_t)(n0 + row) * DM + (k0_) + gc * 8, &sB[b_][c * 8]); \
    }                                                                           \
  } while (0)

  STAGEG(0, 0);
  __syncthreads();
  int buf = 0;
  for (int k0 = 0; k0 < DM; k0 += 32) {
    if (k0 + 32 < DM) STAGEG(k0 + 32, buf ^ 1);
    const char* Ab = (const char*)&sA[0][0] + buf * 8192;
    const char* Bb = (const char*)&sB[0][0] + buf * 8192;
    bf16x8 af[4], bfv[4];
#pragma unroll
    for (int i = 0; i < 4; i++) af[i] = *(const bf16x8*)(Ab + afo + i * 1024);
#pragma unroll
    for (int j = 0; j < 4; j++) bfv[j] = *(const bf16x8*)(Bb + bfo + j * 1024);
    __builtin_amdgcn_s_setprio(1);
#pragma unroll
    for (int i = 0; i < 4; i++)
#pragma unroll
      for (int j = 0; j < 4; j++)
        acc[i][j] = __builtin_amdgcn_mfma_f32_16x16x32_bf16(af[i], bfv[j], acc[i][j], 0, 0, 0);
    __builtin_amdgcn_s_setprio(0);
    __syncthreads();
    buf ^= 1;
  }
#undef STAGEG

#pragma unroll
  for (int i = 0; i < 4; i++) {
#pragma unroll
    for (int j = 0; j < 4; j++) {
      const int gn = n0 + wn + j * 16 + l16;
      const float bb = bias[gn];
#pragma unroll
      for (int r = 0; r < 4; r++) {
        const int gm = m0 + wm + i * 16 + quad * 4 + r;
        const float v = acc[i][j][r] + bb;
        if (z == 3) {
          fdst[(size_t)gm * DM + gn] = v;
        } else {
          const int b_ = gm >> 11, t = gm & 2047;
          const int h_ = gn >> 6, dh = gn & 63;
          if (z == 0) {
            // fold softmax scale AND log2(e): 0.125 * 1.4426950409
            Qb[(((size_t)(b_ * NH + h_)) * TQ + t) * DH + dh] = f2bf(v * 0.18033688011f);
          } else if (z == 1) {
            Kb[(((size_t)(b_ * NH + h_)) * TKTOT + TCACHE + t) * DH + dh] = f2bf(v);
          } else {
            Vtb[(((size_t)(b_ * NH + h_)) * DH + dh) * TKTOT + TCACHE + t] = f2bf(v);
          }
        }
      }
    }
  }
}

// ---------- flash attention v4: 32x32x16 MFMA, QBLK=128, in-register P, split-K=4 ----------
// grid (4 splits, 16 q-blocks, 32 bh); 128 q rows/block; wave w owns rows [q0+32w, +32).
// 2048 blocks -> 8 schedulable blocks/CU (LDS caps residency at 5) to hide the
// inherent exp2 VALU chain (32 quarter-rate exp/tile/lane) under other waves'
// MFMA + ds_read. P stays in-register via cvt_pk + permlane32_swap (T12).
__global__ __launch_bounds__(256, 4) void k_attn(const short* __restrict__ Qb,
                                                 const short* __restrict__ Kb,
                                                 const short* __restrict__ Vtb,
                                                 float* __restrict__ Opart,
                                                 float* __restrict__ Lpart) {
  __shared__ short sK[2][64 * 64];  // [key][dh], chunk^(row&7) swizzle, 2x8KB
  __shared__ short sV[2][64 * 64];  // [dh][key], chunk^(row&7) swizzle, 2x8KB

  const int split = (int)blockIdx.x;
  const int qx = 15 - (int)blockIdx.y;  // longest blocks first
  const int bh = (int)blockIdx.z;
  const int q0 = qx * 128;
  const int tid = threadIdx.x;
  const int wq = tid >> 6;
  const int lane = tid & 63;
  const int l32 = lane & 31;
  const int h = lane >> 5;

  const int nkt = 2 * qx + 34;  // total key tiles for this q-block
  const int kt0 = (nkt * split) >> 2;
  const int kt1 = (nkt * (split + 1)) >> 2;

  const short* Kg = Kb + (size_t)bh * TKTOT * DH;
  const short* Vtg = Vtb + (size_t)bh * DH * TKTOT;

  // staging source pointers (per-thread, kt-invariant part)
  const int c0 = tid, c1 = tid + 256;
  const int r0 = c0 >> 3, g0 = ((c0 & 7) ^ (r0 & 7)) * 8;
  const int r1 = c1 >> 3, g1 = ((c1 & 7) ^ (r1 & 7)) * 8;
  const short* Kst0 = Kg + (size_t)r0 * DH + g0;
  const short* Kst1 = Kg + (size_t)r1 * DH + g1;
  const short* Vst0 = Vtg + (size_t)r0 * TKTOT + g0;
  const short* Vst1 = Vtg + (size_t)r1 * TKTOT + g1;

  // Q fragments straight from global: B-operand, lane holds q=l32, k=8h+i
  const short* Qrow = Qb + ((size_t)bh * TQ + q0 + wq * 32 + l32) * DH;
  bf16x8 qf[4];
#pragma unroll
  for (int s = 0; s < 4; s++) qf[s] = *(const bf16x8*)(Qrow + s * 16 + h * 8);

  // kt-invariant LDS read offsets: row = (32*blk + l32), chunk c=2*ks+h, swz c^(row&7)
  const char* sKc = (const char*)&sK[0][0];
  const char* sVc = (const char*)&sV[0][0];
  const int rx7 = l32 & 7;
  const int base0 = l32 * 128;
  const int base1 = base0 + 4096;
  int co[4];
#pragma unroll
  for (int ks = 0; ks < 4; ks++) co[ks] = ((2 * ks + h) ^ rx7) << 4;

  f32x16 of0 = {0, 0, 0, 0, 0, 0, 0, 0, 0, 0, 0, 0, 0, 0, 0, 0};
  f32x16 of1 = {0, 0, 0, 0, 0, 0, 0, 0, 0, 0, 0, 0, 0, 0, 0, 0};
  float la = 0.f, lb = 0.f, lc = 0.f, ld = 0.f;

#define STAGE(t_, b_)                               \
  do {                                              \
    const size_t koff = (size_t)(t_) * 64 * DH;     \
    const size_t voff = (size_t)(t_) * 64;          \
    short* dK = &sK[b_][0];                         \
    short* dV = &sV[b_][0];                         \
    gld_lds16(Kst0 + koff, dK + c0 * 8);            \
    gld_lds16(Kst1 + koff, dK + c1 * 8);            \
    gld_lds16(Vst0 + voff, dV + c0 * 8);            \
    gld_lds16(Vst1 + voff, dV + c1 * 8);            \
  } while (0)

  STAGE(kt0, 0);
  __syncthreads();
  int buf = 0;

  for (int t = kt0; t < kt1; t++) {
    if (t + 1 < kt1) STAGE(t + 1, buf ^ 1);
    const char* kb_ = sKc + buf * 8192;
    const char* vb_ = sVc + buf * 8192;

    // Sacc = K * Q^T : col(lane&31)=q, row(reg)=key = (r&3)+8*(r>>2)+4h (+32 for blk1)
    f32x16 sacc0 = {0, 0, 0, 0, 0, 0, 0, 0, 0, 0, 0, 0, 0, 0, 0, 0};
    f32x16 sacc1 = {0, 0, 0, 0, 0, 0, 0, 0, 0, 0, 0, 0, 0, 0, 0, 0};
    __builtin_amdgcn_s_setprio(1);
#pragma unroll
    for (int ks = 0; ks < 4; ks++) {
      const bf16x8 kf0 = *(const bf16x8*)(kb_ + base0 + co[ks]);
      const bf16x8 kf1 = *(const bf16x8*)(kb_ + base1 + co[ks]);
      sacc0 = __builtin_amdgcn_mfma_f32_32x32x16_bf16(kf0, qf[ks], sacc0, 0, 0, 0);
      sacc1 = __builtin_amdgcn_mfma_f32_32x32x16_bf16(kf1, qf[ks], sacc1, 0, 0, 0);
    }
    __builtin_amdgcn_s_setprio(0);

    if (t >= nkt - 2) {  // diagonal spans 2 tiles at QBLK=128
      const int qgl = q0 + wq * 32 + l32 + TCACHE;
      const int kb0 = t * 64 + 4 * h;
#pragma unroll
      for (int r = 0; r < 16; r++) {
        const int key = kb0 + (r & 3) + 8 * (r >> 2);
        if (key > qgl) sacc0[r] = -1e30f;
        if (key + 32 > qgl) sacc1[r] = -1e30f;
      }
    }
#pragma unroll
    for (int r = 0; r < 16; r++) {
      const float e0 = exp2fast(sacc0[r]);
      const float e1 = exp2fast(sacc1[r]);
      sacc0[r] = e0;
      sacc1[r] = e1;
      if ((r & 3) == 0) la += e0 + e1;
      else if ((r & 3) == 1) lb += e0 + e1;
      else if ((r & 3) == 2) lc += e0 + e1;
      else ld += e0 + e1;
    }

    // pack + lane-half swap -> PV A-operand: row(lane&31)=q, k=8h+i per kstep
    bf16x8 pa[4];
#pragma unroll
    for (int s = 0; s < 4; s++) {
      const int o = (s & 1) * 8;
      unsigned w0, w1, w2, w3;
      if (s < 2) {
        w0 = pk2(sacc0[o + 0], sacc0[o + 1]);
        w1 = pk2(sacc0[o + 2], sacc0[o + 3]);
        w2 = pk2(sacc0[o + 4], sacc0[o + 5]);
        w3 = pk2(sacc0[o + 6], sacc0[o + 7]);
      } else {
        w0 = pk2(sacc1[o + 0], sacc1[o + 1]);
        w1 = pk2(sacc1[o + 2], sacc1[o + 3]);
        w2 = pk2(sacc1[o + 4], sacc1[o + 5]);
        w3 = pk2(sacc1[o + 6], sacc1[o + 7]);
      }
      plswap(w0, w2);  // w0={lo,lo}, w2={hi,hi}
      plswap(w1, w3);
      union { unsigned u[4]; bf16x8 v; } pu;
      pu.u[0] = w0; pu.u[1] = w1; pu.u[2] = w2; pu.u[3] = w3;
      pa[s] = pu.v;
    }

    // O[q][dh] += P * V : B=V[k][dh] from Vt LDS (lane: dh=32b+l32, t=16ks+8h..+7)
    __builtin_amdgcn_s_setprio(1);
#pragma unroll
    for (int ks = 0; ks < 4; ks++) {
      const bf16x8 vf0 = *(const bf16x8*)(vb_ + base0 + co[ks]);
      const bf16x8 vf1 = *(const bf16x8*)(vb_ + base1 + co[ks]);
      of0 = __builtin_amdgcn_mfma_f32_32x32x16_bf16(pa[ks], vf0, of0, 0, 0, 0);
      of1 = __builtin_amdgcn_mfma_f32_32x32x16_bf16(pa[ks], vf1, of1, 0, 0, 0);
    }
    __builtin_amdgcn_s_setprio(0);
    __syncthreads();
    buf ^= 1;
  }
#undef STAGE

  // write partials: O[128q][64dh] f32 + l[128] f32
  const int pid = (bh * 16 + qx) * 4 + split;
  float* Op = Opart + (size_t)pid * 8192;
#pragma unroll
  for (int r = 0; r < 16; r++) {
    const int ql = wq * 32 + (r & 3) + 8 * (r >> 2) + 4 * h;
    Op[ql * 64 + l32] = of0[r];
    Op[ql * 64 + 32 + l32] = of1[r];
  }
  const float l_lane = (la + lb) + (lc + ld);
  const float l_tot = l_lane + __shfl_xor(l_lane, 32);
  if (h == 0) Lpart[(size_t)pid * 128 + wq * 32 + l32] = l_tot;
}

// ---------- reduce: combine 4 splits, normalize, write AOb bf16 ----------
__global__ __launch_bounds__(256) void k_reduce(const float* __restrict__ Opart,
                                                const float* __restrict__ Lpart,
                                                short* __restrict__ AOb) {
  const int qx = (int)blockIdx.x, bh = (int)blockIdx.y;  // qx: 64-row blocks
  const int b = bh >> 4, hd = bh & 15;
  const int qxb = qx >> 1, hf = qx & 1;
  const int pid = (bh * 16 + qxb) * 4;
  const float* Ob = Opart + (size_t)pid * 8192 + hf * 4096;
  const int t = threadIdx.x;
  const int r_ = t >> 2, c4 = t & 3;
  float l = 0.f;
#pragma unroll
  for (int s = 0; s < 4; s++) l += Lpart[(size_t)(pid + s) * 128 + hf * 64 + r_];
  const float inv = 1.f / l;
  short* dst = AOb + ((size_t)(b * TQ + qx * 64 + r_)) * DM + hd * 64 + c4 * 16;
#pragma unroll
  for (int u = 0; u < 4; u++) {
    const int off = r_ * 64 + c4 * 16 + u * 4;
    float4 a = *(const float4*)(Ob + off);
#pragma unroll
    for (int s = 1; s < 4; s++) {
      const float4 v = *(const float4*)(Ob + (size_t)s * 8192 + off);
      a.x += v.x; a.y += v.y; a.z += v.z; a.w += v.w;
    }
    short4 o;
    o.x = f2bf(a.x * inv);
    o.y = f2bf(a.y * inv);
    o.z = f2bf(a.z * inv);
    o.w = f2bf(a.w * inv);
    *(short4*)(dst + u * 4) = o;
  }
}

// ---------- expand k output: cache part from kc (exact), new part from Kb bf16 ----------
__global__ void k_expand_k(const float* __restrict__ kc, const short* __restrict__ Kb,
                           float* __restrict__ kF) {
  const size_t f4 = (size_t)blockIdx.x * 256 + threadIdx.x;
  const size_t e = f4 * 4;
  const int t = (int)((e >> 6) & 4095);
  float4 v;
  if (t < TCACHE) {
    const int dh = (int)(e & 63);
    const int bh = (int)(e >> 18);
    v = *(const float4*)(kc + ((size_t)(bh * TCACHE + t)) * DH + dh);
  } else {
    const short4 s = *(const short4*)(Kb + e);
    v.x = bf2f(s.x); v.y = bf2f(s.y); v.z = bf2f(s.z); v.w = bf2f(s.w);
  }
  *(float4*)(kF + e) = v;
}

// ---------- expand v output: cache part from vc, new part transposed from Vtb ----------
__global__ void k_expand_v(const float* __restrict__ vc, const short* __restrict__ Vtb,
                           float* __restrict__ vF) {
  __shared__ short tile[64 * 72];
  const int tt = (int)blockIdx.x, bh = (int)blockIdx.y;
  if (tt < 32) {
#pragma unroll
    for (int k2 = 0; k2 < 4; k2++) {
      const int f = threadIdx.x + k2 * 256;
      const int trow = f >> 4, dh4 = f & 15;
      const size_t si = ((size_t)(bh * TCACHE) + tt * 64 + trow) * DH + dh4 * 4;
      const size_t di = ((size_t)(bh * TKTOT) + tt * 64 + trow) * DH + dh4 * 4;
      *(float4*)(vF + di) = *(const float4*)(vc + si);
    }
  } else {
    const int t0 = tt * 64;
#pragma unroll
    for (int k2 = 0; k2 < 4; k2++) {
      const int f = threadIdx.x + k2 * 256;
      const int dh = f >> 4, tc4 = f & 15;
      const short4 s = *(const short4*)(Vtb + ((size_t)(bh * DH + dh)) * TKTOT + t0 + tc4 * 4);
      *(short4*)(&tile[dh * 72 + tc4 * 4]) = s;
    }
    __syncthreads();
#pragma unroll
    for (int k2 = 0; k2 < 4; k2++) {
      const int f = threadIdx.x + k2 * 256;
      const int trow = f >> 4, dh4 = f & 15;
      float4 v;
      v.x = bf2f(tile[(dh4 * 4 + 0) * 72 + trow]);
      v.y = bf2f(tile[(dh4 * 4 + 1) * 72 + trow]);
      v.z = bf2f(tile[(dh4 * 4 + 2) * 72 + trow]);
      v.w = bf2f(tile[(dh4 * 4 + 3) * 72 + trow]);
      *(float4*)(vF + ((size_t)(bh * TKTOT) + t0 + trow) * DH + dh4 * 4) = v;
    }
  }
}

// ---------- host ----------

extern "C" void kernel_launch(void* const* d_in, const int* in_sizes, int n_in,
                              void* d_out, int out_size, void* d_ws, size_t ws_size,
                              hipStream_t stream) {
  const float* x = (const float*)d_in[0];
  const float* kc = (const float*)d_in[1];
  const float* vc = (const float*)d_in[2];
  const float* Wq = (const float*)d_in[3];
  const float* bq = (const float*)d_in[4];
  const float* Wk = (const float*)d_in[5];
  const float* bk = (const float*)d_in[6];
  const float* Wv = (const float*)d_in[7];
  const float* bv = (const float*)d_in[8];
  const float* Wo = (const float*)d_in[9];
  const float* bo = (const float*)d_in[10];

  float* out = (float*)d_out;
  float* kF = out + (size_t)BB * TQ * DM;          // k output region (33.55 MB)
  float* vF = kF + (size_t)BB * NH * TKTOT * DH;   // v output region (33.55 MB)
  // attention partials: O 2048 pids x 8192 f32 = 67.1 MB = kF+vF regions exactly
  // (consumed by k_reduce BEFORE k_expand_* overwrite them); l partials 1 MB
  // live in the out region (free until the final GEMM writes it).
  float* Opart = kF;
  float* Lpart = out;

  char* ws = (char*)d_ws;
  short* xb = (short*)ws;   ws += (size_t)MROWS * DM * 2;
  short* Wt = (short*)ws;   ws += (size_t)4 * DM * DM * 2;
  short* Qb = (short*)ws;   ws += (size_t)BB * NH * TQ * DH * 2;
  short* Kb = (short*)ws;   ws += (size_t)BB * NH * TKTOT * DH * 2;
  short* Vtb = (short*)ws;  ws += (size_t)BB * NH * TKTOT * DH * 2;
  short* AOb = (short*)ws;  // total ws use: 64 MiB

  k_cvt_x<<<4096, 256, 0, stream>>>(x, xb);
  k_transpose_w<<<dim3(32, 32, 4), 256, 0, stream>>>(Wq, Wk, Wv, Wo, Wt);
  k_copy_kcache<<<4096, 256, 0, stream>>>(kc, Kb);
  k_copy_vcache<<<dim3(32, 32), 256, 0, stream>>>(vc, Vtb);
  k_gemm<<<dim3(DM / 128, MROWS / 128, 3), 256, 0, stream>>>(
      xb, Wt, bq, bk, bv, 1, nullptr, Qb, Kb, Vtb);
  k_attn<<<dim3(4, 16, 32), 256, 0, stream>>>(Qb, Kb, Vtb, Opart, Lpart);
  k_reduce<<<dim3(32, 32), 256, 0, stream>>>(Opart, Lpart, AOb);
  k_expand_k<<<8192, 256, 0, stream>>>(kc, Kb, kF);
  k_expand_v<<<dim3(64, 32), 256, 0, stream>>>(vc, Vtb, vF);
  k_gemm<<<dim3(DM / 128, MROWS / 128, 1), 256, 0, stream>>>(
      AOb, Wt + (size_t)3 * DM * DM, bo, bo, bo, 0, out, nullptr, nullptr, nullptr);
}

// Round 4
// 316.988 us; speedup vs baseline: 1.1721x; 1.0777x over previous
//
#include <hip/hip_runtime.h>
#include <hip/hip_bf16.h>
#include <cstdint>
#include <cstddef>

#define DM 1024
#define NH 16
#define DH 64
#define BB 2
#define TQ 2048
#define TCACHE 2048
#define TKTOT 4096
#define MROWS 4096

typedef __attribute__((ext_vector_type(8))) short bf16x8;
typedef __attribute__((ext_vector_type(4))) short bf16x4;
typedef __attribute__((ext_vector_type(4))) float f32x4;
typedef __attribute__((ext_vector_type(16))) float f32x16;

// pack two f32 -> two bf16 in one dword (RNE). gfx950 has NO builtin for
// cvt_pk_bf16 (m240) -- the HW instruction must be used via inline asm;
// the software fallback costs ~12 VALU ops per pair.
__device__ __forceinline__ unsigned pk2(float a, float b) {
  unsigned r;
  asm("v_cvt_pk_bf16_f32 %0, %1, %2" : "=v"(r) : "v"(a), "v"(b));
  return r;
}

__device__ __forceinline__ short f2bf(float f) {
  return (short)(unsigned short)pk2(f, f);
}

__device__ __forceinline__ uint2 pk4(float x, float y, float z, float w) {
  uint2 r;
  r.x = pk2(x, y);
  r.y = pk2(z, w);
  return r;
}

__device__ __forceinline__ float bf2f(short s) {
  union { unsigned u; float f; } v;
  v.u = ((unsigned)(unsigned short)s) << 16;
  return v.f;
}

__device__ __forceinline__ float exp2fast(float x) {
#if __has_builtin(__builtin_amdgcn_exp2f)
  return __builtin_amdgcn_exp2f(x);
#else
  return exp2f(x);
#endif
}

// v_permlane32_swap_b32: a' = {a.lo, b.lo}, b' = {a.hi, b.hi} (lane halves)
__device__ __forceinline__ void plswap(unsigned& a, unsigned& b) {
  asm volatile("v_permlane32_swap_b32 %0, %1" : "+v"(a), "+v"(b));
}

// async global->LDS, 16B/lane. LDS dest must be wave-uniform base + lane*16;
// swizzle goes on the GLOBAL address only (m104/m108).
__device__ __forceinline__ void gld_lds16(const short* g, short* l) {
  __builtin_amdgcn_global_load_lds(
      (const __attribute__((address_space(1))) void*)((uintptr_t)g),
      (__attribute__((address_space(3))) void*)((uintptr_t)l), 16, 0, 0);
}

// ---------- fused prep kernel ----------
// roles by linear blockIdx.x (all 256 threads):
//   [0,4096)      cvt_x:        x f32 -> xb bf16
//   [4096,8192)   transpose_w:  W f32 [K][N] -> Wt bf16 [N][K] (4 weights)
//   [8192,12288)  copy_kcache:  kc f32 -> Kb bf16 (cache part)
//   [12288,13312) copy_vcache:  vc f32 -> Vt bf16 [dh][t] (cache part)
__global__ __launch_bounds__(256) void k_prep(
    const float* __restrict__ x, short* __restrict__ xb,
    const float* __restrict__ W0, const float* __restrict__ W1,
    const float* __restrict__ W2, const float* __restrict__ W3,
    short* __restrict__ Wt,
    const float* __restrict__ kc, short* __restrict__ Kb,
    const float* __restrict__ vc, short* __restrict__ Vtb) {
  __shared__ short lds[64 * 65];
  const int bid = (int)blockIdx.x;
  if (bid < 4096) {
    const size_t i = (size_t)bid * 256 + threadIdx.x;
    const float4 v = ((const float4*)x)[i];
    *(uint2*)(((short4*)xb) + i) = pk4(v.x, v.y, v.z, v.w);
  } else if (bid < 8192) {
    const int local = bid - 4096;
    const int bx = local & 31, by = (local >> 5) & 31, bz = local >> 10;
    short (*tile)[33] = (short(*)[33])lds;
    const float* W = (bz == 0) ? W0 : (bz == 1) ? W1 : (bz == 2) ? W2 : W3;
    short* dst = Wt + (size_t)bz * DM * DM;
    const int k0 = by * 32, n0 = bx * 32;
    const int tx = threadIdx.x & 31, ty = threadIdx.x >> 5;
#pragma unroll
    for (int r = 0; r < 4; r++) {
      const int k = ty + r * 8;
      tile[k][tx] = f2bf(W[(size_t)(k0 + k) * DM + n0 + tx]);
    }
    __syncthreads();
#pragma unroll
    for (int r = 0; r < 4; r++) {
      const int n = ty + r * 8;
      dst[(size_t)(n0 + n) * DM + k0 + tx] = tile[tx][n];
    }
  } else if (bid < 12288) {
    const size_t i = (size_t)(bid - 8192) * 256 + threadIdx.x;
    const float4 v = ((const float4*)kc)[i];
    const size_t e = i * 4;
    const int dh = (int)(e & 63);
    const int t = (int)((e >> 6) & 2047);
    const int bh = (int)(e >> 17);
    *(uint2*)(Kb + ((size_t)bh * TKTOT + t) * DH + dh) = pk4(v.x, v.y, v.z, v.w);
  } else {
    const int local = bid - 12288;
    const int bh = local >> 5;
    const int t0 = (local & 31) * 64;
    short (*tile)[65] = (short(*)[65])lds;
    const int tx = threadIdx.x & 15, ty = threadIdx.x >> 4;
    const float* src = vc + ((size_t)bh * TCACHE + t0) * DH;
#pragma unroll
    for (int r = 0; r < 4; r++) {
      const int t = ty + r * 16;
      const float4 v = *(const float4*)(src + (size_t)t * DH + tx * 4);
      tile[tx * 4 + 0][t] = f2bf(v.x);
      tile[tx * 4 + 1][t] = f2bf(v.y);
      tile[tx * 4 + 2][t] = f2bf(v.z);
      tile[tx * 4 + 3][t] = f2bf(v.w);
    }
    __syncthreads();
    short* vt = Vtb + (size_t)bh * DH * TKTOT + t0;
#pragma unroll
    for (int r = 0; r < 4; r++) {
      const int dh = ty + r * 16;
      short4 o;
      o.x = tile[dh][tx * 4 + 0];
      o.y = tile[dh][tx * 4 + 1];
      o.z = tile[dh][tx * 4 + 2];
      o.w = tile[dh][tx * 4 + 3];
      *(short4*)(vt + (size_t)dh * TKTOT + tx * 4) = o;
    }
  }
}

// ---------- GEMM: C[M,N] = A[M,K] * Bt[N,K]^T + bias ----------
// 128x128 tile (m93/m97 geometry), BK=32, 256 threads (4 waves, 64x64 each),
// double-buffered global_load_lds staging.
__global__ __launch_bounds__(256) void k_gemm(
    const short* __restrict__ A, const short* __restrict__ Bt,
    const float* __restrict__ b0, const float* __restrict__ b1, const float* __restrict__ b2,
    const int is_qkv, float* __restrict__ fdst,
    short* __restrict__ Qb, short* __restrict__ Kb, short* __restrict__ Vtb) {
  const int z = is_qkv ? (int)blockIdx.z : 3;
  const short* Bz = Bt + (is_qkv ? (size_t)z * DM * DM : 0);
  const float* bias = (z == 0 || z == 3) ? b0 : (z == 1 ? b1 : b2);

  __shared__ short sA[2][128 * 32];  // 2 x 8KB
  __shared__ short sB[2][128 * 32];  // 2 x 8KB

  const int m0 = blockIdx.y * 128;
  const int n0 = blockIdx.x * 128;
  const int tid = threadIdx.x;
  const int wv = tid >> 6;
  const int lane = tid & 63;
  const int quad = lane >> 4;
  const int l16 = lane & 15;
  const int wm = (wv >> 1) * 64;
  const int wn = (wv & 1) * 64;

  const f32x4 zero = {0.f, 0.f, 0.f, 0.f};
  f32x4 acc[4][4];
#pragma unroll
  for (int i = 0; i < 4; i++)
#pragma unroll
    for (int j = 0; j < 4; j++) acc[i][j] = zero;

  // kt-invariant fragment read offsets (bytes): row*64 + swizzled-chunk*16
  const int sw = (quad ^ ((l16 >> 1) & 3)) << 4;
  const int afo = (wm + l16) * 64 + sw;
  const int bfo = (wn + l16) * 64 + sw;

#define STAGEG(k0_, b_)                                                         \
  do {                                                                          \
    _Pragma("unroll") for (int s = 0; s < 2; s++) {                             \
      const int c = tid + s * 256;                                              \
      const int row = c >> 2, cs = c & 3;                                       \
      const int gc = cs ^ ((row >> 1) & 3);                                     \
      gld_lds16(A + (size_t)(m0 + row) * DM + (k0_) + gc * 8, &sA[b_][c * 8]);  \
      gld_lds16(Bz + (size_t)(n0 + row) * DM + (k0_) + gc * 8, &sB[b_][c * 8]); \
    }                                                                           \
  } while (0)

  STAGEG(0, 0);
  __syncthreads();
  int buf = 0;
  for (int k0 = 0; k0 < DM; k0 += 32) {
    if (k0 + 32 < DM) STAGEG(k0 + 32, buf ^ 1);
    const char* Ab = (const char*)&sA[0][0] + buf * 8192;
    const char* Bb = (const char*)&sB[0][0] + buf * 8192;
    bf16x8 af[4], bfv[4];
#pragma unroll
    for (int i = 0; i < 4; i++) af[i] = *(const bf16x8*)(Ab + afo + i * 1024);
#pragma unroll
    for (int j = 0; j < 4; j++) bfv[j] = *(const bf16x8*)(Bb + bfo + j * 1024);
    __builtin_amdgcn_s_setprio(1);
#pragma unroll
    for (int i = 0; i < 4; i++)
#pragma unroll
      for (int j = 0; j < 4; j++)
        acc[i][j] = __builtin_amdgcn_mfma_f32_16x16x32_bf16(af[i], bfv[j], acc[i][j], 0, 0, 0);
    __builtin_amdgcn_s_setprio(0);
    __syncthreads();
    buf ^= 1;
  }
#undef STAGEG

#pragma unroll
  for (int i = 0; i < 4; i++) {
#pragma unroll
    for (int j = 0; j < 4; j++) {
      const int gn = n0 + wn + j * 16 + l16;
      const float bb = bias[gn];
#pragma unroll
      for (int r = 0; r < 4; r++) {
        const int gm = m0 + wm + i * 16 + quad * 4 + r;
        const float v = acc[i][j][r] + bb;
        if (z == 3) {
          fdst[(size_t)gm * DM + gn] = v;
        } else {
          const int b_ = gm >> 11, t = gm & 2047;
          const int h_ = gn >> 6, dh = gn & 63;
          if (z == 0) {
            // fold softmax scale AND log2(e): 0.125 * 1.4426950409
            Qb[(((size_t)(b_ * NH + h_)) * TQ + t) * DH + dh] = f2bf(v * 0.18033688011f);
          } else if (z == 1) {
            Kb[(((size_t)(b_ * NH + h_)) * TKTOT + TCACHE + t) * DH + dh] = f2bf(v);
          } else {
            Vtb[(((size_t)(b_ * NH + h_)) * DH + dh) * TKTOT + TCACHE + t] = f2bf(v);
          }
        }
      }
    }
  }
}

// ---------- flash attention: 32x32x16 MFMA, QBLK=128, in-register P, split-K=4 ----------
// grid (4 splits, 16 q-blocks, 32 bh); 128 q rows/block; wave w owns rows [q0+32w, +32).
// P stays in-register via HW cvt_pk (asm) + permlane32_swap (T12). QK MFMA chain
// seeds from a loop-invariant zero C-operand (no per-tile acc re-zeroing).
__global__ __launch_bounds__(256, 4) void k_attn(const short* __restrict__ Qb,
                                                 const short* __restrict__ Kb,
                                                 const short* __restrict__ Vtb,
                                                 float* __restrict__ Opart,
                                                 float* __restrict__ Lpart) {
  __shared__ short sK[2][64 * 64];  // [key][dh], chunk^(row&7) swizzle, 2x8KB
  __shared__ short sV[2][64 * 64];  // [dh][key], chunk^(row&7) swizzle, 2x8KB

  const int split = (int)blockIdx.x;
  const int qx = 15 - (int)blockIdx.y;  // longest blocks first
  const int bh = (int)blockIdx.z;
  const int q0 = qx * 128;
  const int tid = threadIdx.x;
  const int wq = tid >> 6;
  const int lane = tid & 63;
  const int l32 = lane & 31;
  const int h = lane >> 5;

  const int nkt = 2 * qx + 34;  // total key tiles for this q-block
  const int kt0 = (nkt * split) >> 2;
  const int kt1 = (nkt * (split + 1)) >> 2;

  const short* Kg = Kb + (size_t)bh * TKTOT * DH;
  const short* Vtg = Vtb + (size_t)bh * DH * TKTOT;

  // staging source pointers (per-thread, kt-invariant part)
  const int c0 = tid, c1 = tid + 256;
  const int r0 = c0 >> 3, g0 = ((c0 & 7) ^ (r0 & 7)) * 8;
  const int r1 = c1 >> 3, g1 = ((c1 & 7) ^ (r1 & 7)) * 8;
  const short* Kst0 = Kg + (size_t)r0 * DH + g0;
  const short* Kst1 = Kg + (size_t)r1 * DH + g1;
  const short* Vst0 = Vtg + (size_t)r0 * TKTOT + g0;
  const short* Vst1 = Vtg + (size_t)r1 * TKTOT + g1;

  // Q fragments straight from global: B-operand, lane holds q=l32, k=8h+i
  const short* Qrow = Qb + ((size_t)bh * TQ + q0 + wq * 32 + l32) * DH;
  bf16x8 qf[4];
#pragma unroll
  for (int s = 0; s < 4; s++) qf[s] = *(const bf16x8*)(Qrow + s * 16 + h * 8);

  // kt-invariant LDS read offsets: row = (32*blk + l32), chunk c=2*ks+h, swz c^(row&7)
  const char* sKc = (const char*)&sK[0][0];
  const char* sVc = (const char*)&sV[0][0];
  const int rx7 = l32 & 7;
  const int base0 = l32 * 128;
  const int base1 = base0 + 4096;
  int co[4];
#pragma unroll
  for (int ks = 0; ks < 4; ks++) co[ks] = ((2 * ks + h) ^ rx7) << 4;

  const f32x16 zerov = {0, 0, 0, 0, 0, 0, 0, 0, 0, 0, 0, 0, 0, 0, 0, 0};
  f32x16 of0 = zerov;
  f32x16 of1 = zerov;
  float la = 0.f, lb = 0.f, lc = 0.f, ld = 0.f;

#define STAGE(t_, b_)                               \
  do {                                              \
    const size_t koff = (size_t)(t_) * 64 * DH;     \
    const size_t voff = (size_t)(t_) * 64;          \
    short* dK = &sK[b_][0];                         \
    short* dV = &sV[b_][0];                         \
    gld_lds16(Kst0 + koff, dK + c0 * 8);            \
    gld_lds16(Kst1 + koff, dK + c1 * 8);            \
    gld_lds16(Vst0 + voff, dV + c0 * 8);            \
    gld_lds16(Vst1 + voff, dV + c1 * 8);            \
  } while (0)

  STAGE(kt0, 0);
  __syncthreads();
  int buf = 0;

  for (int t = kt0; t < kt1; t++) {
    if (t + 1 < kt1) STAGE(t + 1, buf ^ 1);
    const char* kb_ = sKc + buf * 8192;
    const char* vb_ = sVc + buf * 8192;

    // Sacc = K * Q^T : col(lane&31)=q, row(reg)=key = (r&3)+8*(r>>2)+4h (+32 for blk1)
    f32x16 sacc0, sacc1;
    __builtin_amdgcn_s_setprio(1);
    {
      const bf16x8 kf0 = *(const bf16x8*)(kb_ + base0 + co[0]);
      const bf16x8 kf1 = *(const bf16x8*)(kb_ + base1 + co[0]);
      sacc0 = __builtin_amdgcn_mfma_f32_32x32x16_bf16(kf0, qf[0], zerov, 0, 0, 0);
      sacc1 = __builtin_amdgcn_mfma_f32_32x32x16_bf16(kf1, qf[0], zerov, 0, 0, 0);
    }
#pragma unroll
    for (int ks = 1; ks < 4; ks++) {
      const bf16x8 kf0 = *(const bf16x8*)(kb_ + base0 + co[ks]);
      const bf16x8 kf1 = *(const bf16x8*)(kb_ + base1 + co[ks]);
      sacc0 = __builtin_amdgcn_mfma_f32_32x32x16_bf16(kf0, qf[ks], sacc0, 0, 0, 0);
      sacc1 = __builtin_amdgcn_mfma_f32_32x32x16_bf16(kf1, qf[ks], sacc1, 0, 0, 0);
    }
    __builtin_amdgcn_s_setprio(0);

    if (t >= nkt - 2) {  // diagonal spans 2 tiles at QBLK=128
      const int qgl = q0 + wq * 32 + l32 + TCACHE;
      const int kb0 = t * 64 + 4 * h;
#pragma unroll
      for (int r = 0; r < 16; r++) {
        const int key = kb0 + (r & 3) + 8 * (r >> 2);
        if (key > qgl) sacc0[r] = -1e30f;
        if (key + 32 > qgl) sacc1[r] = -1e30f;
      }
    }
#pragma unroll
    for (int r = 0; r < 16; r++) {
      const float e0 = exp2fast(sacc0[r]);
      const float e1 = exp2fast(sacc1[r]);
      sacc0[r] = e0;
      sacc1[r] = e1;
      if ((r & 3) == 0) la += e0 + e1;
      else if ((r & 3) == 1) lb += e0 + e1;
      else if ((r & 3) == 2) lc += e0 + e1;
      else ld += e0 + e1;
    }

    // pack + lane-half swap -> PV A-operand: row(lane&31)=q, k=8h+i per kstep
    bf16x8 pa[4];
#pragma unroll
    for (int s = 0; s < 4; s++) {
      const int o = (s & 1) * 8;
      unsigned w0, w1, w2, w3;
      if (s < 2) {
        w0 = pk2(sacc0[o + 0], sacc0[o + 1]);
        w1 = pk2(sacc0[o + 2], sacc0[o + 3]);
        w2 = pk2(sacc0[o + 4], sacc0[o + 5]);
        w3 = pk2(sacc0[o + 6], sacc0[o + 7]);
      } else {
        w0 = pk2(sacc1[o + 0], sacc1[o + 1]);
        w1 = pk2(sacc1[o + 2], sacc1[o + 3]);
        w2 = pk2(sacc1[o + 4], sacc1[o + 5]);
        w3 = pk2(sacc1[o + 6], sacc1[o + 7]);
      }
      plswap(w0, w2);  // w0={lo,lo}, w2={hi,hi}
      plswap(w1, w3);
      union { unsigned u[4]; bf16x8 v; } pu;
      pu.u[0] = w0; pu.u[1] = w1; pu.u[2] = w2; pu.u[3] = w3;
      pa[s] = pu.v;
    }

    // O[q][dh] += P * V : B=V[k][dh] from Vt LDS (lane: dh=32b+l32, t=16ks+8h..+7)
    __builtin_amdgcn_s_setprio(1);
#pragma unroll
    for (int ks = 0; ks < 4; ks++) {
      const bf16x8 vf0 = *(const bf16x8*)(vb_ + base0 + co[ks]);
      const bf16x8 vf1 = *(const bf16x8*)(vb_ + base1 + co[ks]);
      of0 = __builtin_amdgcn_mfma_f32_32x32x16_bf16(pa[ks], vf0, of0, 0, 0, 0);
      of1 = __builtin_amdgcn_mfma_f32_32x32x16_bf16(pa[ks], vf1, of1, 0, 0, 0);
    }
    __builtin_amdgcn_s_setprio(0);
    __syncthreads();
    buf ^= 1;
  }
#undef STAGE

  // write partials: O[128q][64dh] f32 + l[128] f32
  const int pid = (bh * 16 + qx) * 4 + split;
  float* Op = Opart + (size_t)pid * 8192;
#pragma unroll
  for (int r = 0; r < 16; r++) {
    const int ql = wq * 32 + (r & 3) + 8 * (r >> 2) + 4 * h;
    Op[ql * 64 + l32] = of0[r];
    Op[ql * 64 + 32 + l32] = of1[r];
  }
  const float l_lane = (la + lb) + (lc + ld);
  const float l_tot = l_lane + __shfl_xor(l_lane, 32);
  if (h == 0) Lpart[(size_t)pid * 128 + wq * 32 + l32] = l_tot;
}

// ---------- reduce: combine 4 splits, normalize, write AOb bf16 ----------
__global__ __launch_bounds__(256) void k_reduce(const float* __restrict__ Opart,
                                                const float* __restrict__ Lpart,
                                                short* __restrict__ AOb) {
  const int qx = (int)blockIdx.x, bh = (int)blockIdx.y;  // qx: 64-row blocks
  const int b = bh >> 4, hd = bh & 15;
  const int qxb = qx >> 1, hf = qx & 1;
  const int pid = (bh * 16 + qxb) * 4;
  const float* Ob = Opart + (size_t)pid * 8192 + hf * 4096;
  const int t = threadIdx.x;
  const int r_ = t >> 2, c4 = t & 3;
  float l = 0.f;
#pragma unroll
  for (int s = 0; s < 4; s++) l += Lpart[(size_t)(pid + s) * 128 + hf * 64 + r_];
  const float inv = 1.f / l;
  short* dst = AOb + ((size_t)(b * TQ + qx * 64 + r_)) * DM + hd * 64 + c4 * 16;
#pragma unroll
  for (int u = 0; u < 4; u++) {
    const int off = r_ * 64 + c4 * 16 + u * 4;
    float4 a = *(const float4*)(Ob + off);
#pragma unroll
    for (int s = 1; s < 4; s++) {
      const float4 v = *(const float4*)(Ob + (size_t)s * 8192 + off);
      a.x += v.x; a.y += v.y; a.z += v.z; a.w += v.w;
    }
    *(uint2*)(dst + u * 4) = pk4(a.x * inv, a.y * inv, a.z * inv, a.w * inv);
  }
}

// ---------- fused expand kernel ----------
// roles by linear blockIdx.x:
//   [0,8192)      expand_k: kF f32 from kc (cache, exact) / Kb bf16 (new)
//   [8192,10240)  expand_v: vF f32 from vc (cache) / Vtb transposed (new)
__global__ __launch_bounds__(256) void k_expand(const float* __restrict__ kc,
                                                const short* __restrict__ Kb,
                                                float* __restrict__ kF,
                                                const float* __restrict__ vc,
                                                const short* __restrict__ Vtb,
                                                float* __restrict__ vF) {
  __shared__ short tile[64 * 72];
  const int bid = (int)blockIdx.x;
  if (bid < 8192) {
    const size_t f4 = (size_t)bid * 256 + threadIdx.x;
    const size_t e = f4 * 4;
    const int t = (int)((e >> 6) & 4095);
    float4 v;
    if (t < TCACHE) {
      const int dh = (int)(e & 63);
      const int bh = (int)(e >> 18);
      v = *(const float4*)(kc + ((size_t)(bh * TCACHE + t)) * DH + dh);
    } else {
      const short4 s = *(const short4*)(Kb + e);
      v.x = bf2f(s.x); v.y = bf2f(s.y); v.z = bf2f(s.z); v.w = bf2f(s.w);
    }
    *(float4*)(kF + e) = v;
  } else {
    const int local = bid - 8192;
    const int tt = local & 63, bh = local >> 6;
    if (tt < 32) {
#pragma unroll
      for (int k2 = 0; k2 < 4; k2++) {
        const int f = threadIdx.x + k2 * 256;
        const int trow = f >> 4, dh4 = f & 15;
        const size_t si = ((size_t)(bh * TCACHE) + tt * 64 + trow) * DH + dh4 * 4;
        const size_t di = ((size_t)(bh * TKTOT) + tt * 64 + trow) * DH + dh4 * 4;
        *(float4*)(vF + di) = *(const float4*)(vc + si);
      }
    } else {
      const int t0 = tt * 64;
#pragma unroll
      for (int k2 = 0; k2 < 4; k2++) {
        const int f = threadIdx.x + k2 * 256;
        const int dh = f >> 4, tc4 = f & 15;
        const short4 s = *(const short4*)(Vtb + ((size_t)(bh * DH + dh)) * TKTOT + t0 + tc4 * 4);
        *(short4*)(&tile[dh * 72 + tc4 * 4]) = s;
      }
      __syncthreads();
#pragma unroll
      for (int k2 = 0; k2 < 4; k2++) {
        const int f = threadIdx.x + k2 * 256;
        const int trow = f >> 4, dh4 = f & 15;
        float4 v;
        v.x = bf2f(tile[(dh4 * 4 + 0) * 72 + trow]);
        v.y = bf2f(tile[(dh4 * 4 + 1) * 72 + trow]);
        v.z = bf2f(tile[(dh4 * 4 + 2) * 72 + trow]);
        v.w = bf2f(tile[(dh4 * 4 + 3) * 72 + trow]);
        *(float4*)(vF + ((size_t)(bh * TKTOT) + t0 + trow) * DH + dh4 * 4) = v;
      }
    }
  }
}

// ---------- host ----------

extern "C" void kernel_launch(void* const* d_in, const int* in_sizes, int n_in,
                              void* d_out, int out_size, void* d_ws, size_t ws_size,
                              hipStream_t stream) {
  const float* x = (const float*)d_in[0];
  const float* kc = (const float*)d_in[1];
  const float* vc = (const float*)d_in[2];
  const float* Wq = (const float*)d_in[3];
  const float* bq = (const float*)d_in[4];
  const float* Wk = (const float*)d_in[5];
  const float* bk = (const float*)d_in[6];
  const float* Wv = (const float*)d_in[7];
  const float* bv = (const float*)d_in[8];
  const float* Wo = (const float*)d_in[9];
  const float* bo = (const float*)d_in[10];

  float* out = (float*)d_out;
  float* kF = out + (size_t)BB * TQ * DM;          // k output region (33.55 MB)
  float* vF = kF + (size_t)BB * NH * TKTOT * DH;   // v output region (33.55 MB)
  // attention partials: O 2048 pids x 8192 f32 = 67.1 MB = kF+vF regions exactly
  // (consumed by k_reduce BEFORE k_expand overwrites them); l partials 1 MB
  // live in the out region (free until the final GEMM writes it).
  float* Opart = kF;
  float* Lpart = out;

  char* ws = (char*)d_ws;
  short* xb = (short*)ws;   ws += (size_t)MROWS * DM * 2;
  short* Wt = (short*)ws;   ws += (size_t)4 * DM * DM * 2;
  short* Qb = (short*)ws;   ws += (size_t)BB * NH * TQ * DH * 2;
  short* Kb = (short*)ws;   ws += (size_t)BB * NH * TKTOT * DH * 2;
  short* Vtb = (short*)ws;  ws += (size_t)BB * NH * TKTOT * DH * 2;
  short* AOb = (short*)ws;  // total ws use: 64 MiB

  k_prep<<<13312, 256, 0, stream>>>(x, xb, Wq, Wk, Wv, Wo, Wt, kc, Kb, vc, Vtb);
  k_gemm<<<dim3(DM / 128, MROWS / 128, 3), 256, 0, stream>>>(
      xb, Wt, bq, bk, bv, 1, nullptr, Qb, Kb, Vtb);
  k_attn<<<dim3(4, 16, 32), 256, 0, stream>>>(Qb, Kb, Vtb, Opart, Lpart);
  k_reduce<<<dim3(32, 32), 256, 0, stream>>>(Opart, Lpart, AOb);
  k_expand<<<10240, 256, 0, stream>>>(kc, Kb, kF, vc, Vtb, vF);
  k_gemm<<<dim3(DM / 128, MROWS / 128, 1), 256, 0, stream>>>(
      AOb, Wt + (size_t)3 * DM * DM, bo, bo, bo, 0, out, nullptr, nullptr, nullptr);
}

// Round 5
// 270.958 us; speedup vs baseline: 1.3712x; 1.1699x over previous
//
#include <hip/hip_runtime.h>
#include <hip/hip_bf16.h>
#include <cstdint>
#include <cstddef>

#define DM 1024
#define NH 16
#define DH 64
#define BB 2
#define TQ 2048
#define TCACHE 2048
#define TKTOT 4096
#define MROWS 4096

typedef __attribute__((ext_vector_type(8))) short bf16x8;
typedef __attribute__((ext_vector_type(4))) short bf16x4;
typedef __attribute__((ext_vector_type(4))) float f32x4;
typedef __attribute__((ext_vector_type(16))) float f32x16;

// pack two f32 -> two bf16 in one dword (RNE). gfx950 has NO builtin for
// cvt_pk_bf16 (m240) -- the HW instruction must be used via inline asm;
// the software fallback costs ~12 VALU ops per pair.
__device__ __forceinline__ unsigned pk2(float a, float b) {
  unsigned r;
  asm("v_cvt_pk_bf16_f32 %0, %1, %2" : "=v"(r) : "v"(a), "v"(b));
  return r;
}

__device__ __forceinline__ short f2bf(float f) {
  return (short)(unsigned short)pk2(f, f);
}

__device__ __forceinline__ uint2 pk4(float x, float y, float z, float w) {
  uint2 r;
  r.x = pk2(x, y);
  r.y = pk2(z, w);
  return r;
}

__device__ __forceinline__ float bf2f(short s) {
  union { unsigned u; float f; } v;
  v.u = ((unsigned)(unsigned short)s) << 16;
  return v.f;
}

__device__ __forceinline__ float exp2fast(float x) {
#if __has_builtin(__builtin_amdgcn_exp2f)
  return __builtin_amdgcn_exp2f(x);
#else
  return exp2f(x);
#endif
}

// v_permlane32_swap_b32: a' = {a.lo, b.lo}, b' = {a.hi, b.hi} (lane halves)
__device__ __forceinline__ void plswap(unsigned& a, unsigned& b) {
  asm volatile("v_permlane32_swap_b32 %0, %1" : "+v"(a), "+v"(b));
}

// async global->LDS, 16B/lane. LDS dest must be wave-uniform base + lane*16;
// swizzle goes on the GLOBAL address only (m104/m108).
__device__ __forceinline__ void gld_lds16(const short* g, short* l) {
  __builtin_amdgcn_global_load_lds(
      (const __attribute__((address_space(1))) void*)((uintptr_t)g),
      (__attribute__((address_space(3))) void*)((uintptr_t)l), 16, 0, 0);
}

// ---------- fused prep kernel ----------
// roles by linear blockIdx.x (all 256 threads):
//   [0,4096)      cvt_x:        x f32 -> xb bf16
//   [4096,8192)   transpose_w:  W f32 [K][N] -> Wt bf16 [N][K] (4 weights)
//   [8192,12288)  copy_kcache:  kc f32 -> Kb bf16 (cache part)
//   [12288,13312) copy_vcache:  vc f32 -> Vt bf16 [dh][t] (cache part)
__global__ __launch_bounds__(256) void k_prep(
    const float* __restrict__ x, short* __restrict__ xb,
    const float* __restrict__ W0, const float* __restrict__ W1,
    const float* __restrict__ W2, const float* __restrict__ W3,
    short* __restrict__ Wt,
    const float* __restrict__ kc, short* __restrict__ Kb,
    const float* __restrict__ vc, short* __restrict__ Vtb) {
  __shared__ short lds[64 * 65];
  const int bid = (int)blockIdx.x;
  if (bid < 4096) {
    const size_t i = (size_t)bid * 256 + threadIdx.x;
    const float4 v = ((const float4*)x)[i];
    *(uint2*)(((short4*)xb) + i) = pk4(v.x, v.y, v.z, v.w);
  } else if (bid < 8192) {
    const int local = bid - 4096;
    const int bx = local & 31, by = (local >> 5) & 31, bz = local >> 10;
    short (*tile)[33] = (short(*)[33])lds;
    const float* W = (bz == 0) ? W0 : (bz == 1) ? W1 : (bz == 2) ? W2 : W3;
    short* dst = Wt + (size_t)bz * DM * DM;
    const int k0 = by * 32, n0 = bx * 32;
    const int tx = threadIdx.x & 31, ty = threadIdx.x >> 5;
#pragma unroll
    for (int r = 0; r < 4; r++) {
      const int k = ty + r * 8;
      tile[k][tx] = f2bf(W[(size_t)(k0 + k) * DM + n0 + tx]);
    }
    __syncthreads();
#pragma unroll
    for (int r = 0; r < 4; r++) {
      const int n = ty + r * 8;
      dst[(size_t)(n0 + n) * DM + k0 + tx] = tile[tx][n];
    }
  } else if (bid < 12288) {
    const size_t i = (size_t)(bid - 8192) * 256 + threadIdx.x;
    const float4 v = ((const float4*)kc)[i];
    const size_t e = i * 4;
    const int dh = (int)(e & 63);
    const int t = (int)((e >> 6) & 2047);
    const int bh = (int)(e >> 17);
    *(uint2*)(Kb + ((size_t)bh * TKTOT + t) * DH + dh) = pk4(v.x, v.y, v.z, v.w);
  } else {
    const int local = bid - 12288;
    const int bh = local >> 5;
    const int t0 = (local & 31) * 64;
    short (*tile)[65] = (short(*)[65])lds;
    const int tx = threadIdx.x & 15, ty = threadIdx.x >> 4;
    const float* src = vc + ((size_t)bh * TCACHE + t0) * DH;
#pragma unroll
    for (int r = 0; r < 4; r++) {
      const int t = ty + r * 16;
      const float4 v = *(const float4*)(src + (size_t)t * DH + tx * 4);
      tile[tx * 4 + 0][t] = f2bf(v.x);
      tile[tx * 4 + 1][t] = f2bf(v.y);
      tile[tx * 4 + 2][t] = f2bf(v.z);
      tile[tx * 4 + 3][t] = f2bf(v.w);
    }
    __syncthreads();
    short* vt = Vtb + (size_t)bh * DH * TKTOT + t0;
#pragma unroll
    for (int r = 0; r < 4; r++) {
      const int dh = ty + r * 16;
      short4 o;
      o.x = tile[dh][tx * 4 + 0];
      o.y = tile[dh][tx * 4 + 1];
      o.z = tile[dh][tx * 4 + 2];
      o.w = tile[dh][tx * 4 + 3];
      *(short4*)(vt + (size_t)dh * TKTOT + tx * 4) = o;
    }
  }
}

// ---------- GEMM: C[M,N] = A[M,K] * Bt[N,K]^T + bias ----------
// 128x128 tile (m93/m97 geometry), BK=32, 256 threads (4 waves, 64x64 each),
// double-buffered global_load_lds staging.
__global__ __launch_bounds__(256) void k_gemm(
    const short* __restrict__ A, const short* __restrict__ Bt,
    const float* __restrict__ b0, const float* __restrict__ b1, const float* __restrict__ b2,
    const int is_qkv, float* __restrict__ fdst,
    short* __restrict__ Qb, short* __restrict__ Kb, short* __restrict__ Vtb) {
  const int z = is_qkv ? (int)blockIdx.z : 3;
  const short* Bz = Bt + (is_qkv ? (size_t)z * DM * DM : 0);
  const float* bias = (z == 0 || z == 3) ? b0 : (z == 1 ? b1 : b2);

  __shared__ short sA[2][128 * 32];  // 2 x 8KB
  __shared__ short sB[2][128 * 32];  // 2 x 8KB

  const int m0 = blockIdx.y * 128;
  const int n0 = blockIdx.x * 128;
  const int tid = threadIdx.x;
  const int wv = tid >> 6;
  const int lane = tid & 63;
  const int quad = lane >> 4;
  const int l16 = lane & 15;
  const int wm = (wv >> 1) * 64;
  const int wn = (wv & 1) * 64;

  const f32x4 zero = {0.f, 0.f, 0.f, 0.f};
  f32x4 acc[4][4];
#pragma unroll
  for (int i = 0; i < 4; i++)
#pragma unroll
    for (int j = 0; j < 4; j++) acc[i][j] = zero;

  // kt-invariant fragment read offsets (bytes): row*64 + swizzled-chunk*16
  const int sw = (quad ^ ((l16 >> 1) & 3)) << 4;
  const int afo = (wm + l16) * 64 + sw;
  const int bfo = (wn + l16) * 64 + sw;

#define STAGEG(k0_, b_)                                                         \
  do {                                                                          \
    _Pragma("unroll") for (int s = 0; s < 2; s++) {                             \
      const int c = tid + s * 256;                                              \
      const int row = c >> 2, cs = c & 3;                                       \
      const int gc = cs ^ ((row >> 1) & 3);                                     \
      gld_lds16(A + (size_t)(m0 + row) * DM + (k0_) + gc * 8, &sA[b_][c * 8]);  \
      gld_lds16(Bz + (size_t)(n0 + row) * DM + (k0_) + gc * 8, &sB[b_][c * 8]); \
    }                                                                           \
  } while (0)

  STAGEG(0, 0);
  __syncthreads();
  int buf = 0;
  for (int k0 = 0; k0 < DM; k0 += 32) {
    if (k0 + 32 < DM) STAGEG(k0 + 32, buf ^ 1);
    const char* Ab = (const char*)&sA[0][0] + buf * 8192;
    const char* Bb = (const char*)&sB[0][0] + buf * 8192;
    bf16x8 af[4], bfv[4];
#pragma unroll
    for (int i = 0; i < 4; i++) af[i] = *(const bf16x8*)(Ab + afo + i * 1024);
#pragma unroll
    for (int j = 0; j < 4; j++) bfv[j] = *(const bf16x8*)(Bb + bfo + j * 1024);
    __builtin_amdgcn_s_setprio(1);
#pragma unroll
    for (int i = 0; i < 4; i++)
#pragma unroll
      for (int j = 0; j < 4; j++)
        acc[i][j] = __builtin_amdgcn_mfma_f32_16x16x32_bf16(af[i], bfv[j], acc[i][j], 0, 0, 0);
    __builtin_amdgcn_s_setprio(0);
    __syncthreads();
    buf ^= 1;
  }
#undef STAGEG

#pragma unroll
  for (int i = 0; i < 4; i++) {
#pragma unroll
    for (int j = 0; j < 4; j++) {
      const int gn = n0 + wn + j * 16 + l16;
      const float bb = bias[gn];
#pragma unroll
      for (int r = 0; r < 4; r++) {
        const int gm = m0 + wm + i * 16 + quad * 4 + r;
        const float v = acc[i][j][r] + bb;
        if (z == 3) {
          fdst[(size_t)gm * DM + gn] = v;
        } else {
          const int b_ = gm >> 11, t = gm & 2047;
          const int h_ = gn >> 6, dh = gn & 63;
          if (z == 0) {
            // fold softmax scale AND log2(e): 0.125 * 1.4426950409
            Qb[(((size_t)(b_ * NH + h_)) * TQ + t) * DH + dh] = f2bf(v * 0.18033688011f);
          } else if (z == 1) {
            Kb[(((size_t)(b_ * NH + h_)) * TKTOT + TCACHE + t) * DH + dh] = f2bf(v);
          } else {
            Vtb[(((size_t)(b_ * NH + h_)) * DH + dh) * TKTOT + TCACHE + t] = f2bf(v);
          }
        }
      }
    }
  }
}

// ---------- fused attention + expand ----------
// roles by blockIdx.x:
//   [0,512)       flash attention, QBLK=128, NO split-K: each block does its full
//                 key range, normalizes in-kernel (l broadcast via 128B of dead
//                 LDS), writes bf16 AOb directly. No O/L partials, no reduce.
//                 512 blocks = exactly 2/CU, all co-resident at t=0; qx map
//                 (y<8 ? 15-y : y-8) pairs long+short blocks to a constant
//                 98-tile load per CU.
//   [512,8704)    expand_k: kF f32 from kc (cache, exact) / Kb bf16 (new)
//   [8704,10752)  expand_v: vF f32 from vc (cache) / Vtb transposed (new)
// expand blocks are pure streaming and backfill the 3 spare LDS slots per CU,
// running under the attention blocks' latency shadow (attn uses ~2.2 of
// 6.3 TB/s; pipes are complementary).
__global__ __launch_bounds__(256, 4) void k_attn_expand(
    const short* __restrict__ Qb, const short* __restrict__ Kb,
    const short* __restrict__ Vtb, short* __restrict__ AOb,
    const float* __restrict__ kc, float* __restrict__ kF,
    const float* __restrict__ vc, float* __restrict__ vF) {
  __shared__ short SH[16384];  // 32KB: attn sK[2][4096]+sV[2][4096]; expand tile

  const int bid = (int)blockIdx.x;
  if (bid < 512) {
    // ---------------- attention role ----------------
    const int y = bid >> 5;
    const int bh = bid & 31;
    const int qx = (y < 8) ? (15 - y) : (y - 8);
    const int q0 = qx * 128;
    const int tid = threadIdx.x;
    const int wq = tid >> 6;
    const int lane = tid & 63;
    const int l32 = lane & 31;
    const int h = lane >> 5;

    const int nkt = 2 * qx + 34;  // total key tiles for this q-block

    const short* Kg = Kb + (size_t)bh * TKTOT * DH;
    const short* Vtg = Vtb + (size_t)bh * DH * TKTOT;

    // staging source pointers (per-thread, kt-invariant part)
    const int c0 = tid, c1 = tid + 256;
    const int r0 = c0 >> 3, g0 = ((c0 & 7) ^ (r0 & 7)) * 8;
    const int r1 = c1 >> 3, g1 = ((c1 & 7) ^ (r1 & 7)) * 8;
    const short* Kst0 = Kg + (size_t)r0 * DH + g0;
    const short* Kst1 = Kg + (size_t)r1 * DH + g1;
    const short* Vst0 = Vtg + (size_t)r0 * TKTOT + g0;
    const short* Vst1 = Vtg + (size_t)r1 * TKTOT + g1;

    // Q fragments straight from global: B-operand, lane holds q=l32, k=8h+i
    const short* Qrow = Qb + ((size_t)bh * TQ + q0 + wq * 32 + l32) * DH;
    bf16x8 qf[4];
#pragma unroll
    for (int s = 0; s < 4; s++) qf[s] = *(const bf16x8*)(Qrow + s * 16 + h * 8);

    // kt-invariant LDS read offsets: row = (32*blk + l32), chunk c=2*ks+h, swz c^(row&7)
    const char* sKc = (const char*)SH;           // sK: bytes [0, 16384)
    const char* sVc = (const char*)SH + 16384;   // sV: bytes [16384, 32768)
    const int rx7 = l32 & 7;
    const int base0 = l32 * 128;
    const int base1 = base0 + 4096;
    int co[4];
#pragma unroll
    for (int ks = 0; ks < 4; ks++) co[ks] = ((2 * ks + h) ^ rx7) << 4;

    const f32x16 zerov = {0, 0, 0, 0, 0, 0, 0, 0, 0, 0, 0, 0, 0, 0, 0, 0};
    f32x16 of0 = zerov;
    f32x16 of1 = zerov;
    float la = 0.f, lb = 0.f, lc = 0.f, ld = 0.f;

#define STAGE(t_, b_)                                    \
    do {                                                 \
      const size_t koff = (size_t)(t_) * 64 * DH;        \
      const size_t voff = (size_t)(t_) * 64;             \
      short* dK = SH + (b_)*4096;                        \
      short* dV = SH + 8192 + (b_)*4096;                 \
      gld_lds16(Kst0 + koff, dK + c0 * 8);               \
      gld_lds16(Kst1 + koff, dK + c1 * 8);               \
      gld_lds16(Vst0 + voff, dV + c0 * 8);               \
      gld_lds16(Vst1 + voff, dV + c1 * 8);               \
    } while (0)

    STAGE(0, 0);
    __syncthreads();
    int buf = 0;

    for (int t = 0; t < nkt; t++) {
      if (t + 1 < nkt) STAGE(t + 1, buf ^ 1);
      const char* kb_ = sKc + buf * 8192;
      const char* vb_ = sVc + buf * 8192;

      // Sacc = K * Q^T : col(lane&31)=q, row(reg)=key = (r&3)+8*(r>>2)+4h (+32 blk1)
      f32x16 sacc0, sacc1;
      __builtin_amdgcn_s_setprio(1);
      {
        const bf16x8 kf0 = *(const bf16x8*)(kb_ + base0 + co[0]);
        const bf16x8 kf1 = *(const bf16x8*)(kb_ + base1 + co[0]);
        sacc0 = __builtin_amdgcn_mfma_f32_32x32x16_bf16(kf0, qf[0], zerov, 0, 0, 0);
        sacc1 = __builtin_amdgcn_mfma_f32_32x32x16_bf16(kf1, qf[0], zerov, 0, 0, 0);
      }
#pragma unroll
      for (int ks = 1; ks < 4; ks++) {
        const bf16x8 kf0 = *(const bf16x8*)(kb_ + base0 + co[ks]);
        const bf16x8 kf1 = *(const bf16x8*)(kb_ + base1 + co[ks]);
        sacc0 = __builtin_amdgcn_mfma_f32_32x32x16_bf16(kf0, qf[ks], sacc0, 0, 0, 0);
        sacc1 = __builtin_amdgcn_mfma_f32_32x32x16_bf16(kf1, qf[ks], sacc1, 0, 0, 0);
      }
      __builtin_amdgcn_s_setprio(0);

      if (t >= nkt - 2) {  // diagonal spans 2 tiles at QBLK=128
        const int qgl = q0 + wq * 32 + l32 + TCACHE;
        const int kb0 = t * 64 + 4 * h;
#pragma unroll
        for (int r = 0; r < 16; r++) {
          const int key = kb0 + (r & 3) + 8 * (r >> 2);
          if (key > qgl) sacc0[r] = -1e30f;
          if (key + 32 > qgl) sacc1[r] = -1e30f;
        }
      }
#pragma unroll
      for (int r = 0; r < 16; r++) {
        const float e0 = exp2fast(sacc0[r]);
        const float e1 = exp2fast(sacc1[r]);
        sacc0[r] = e0;
        sacc1[r] = e1;
        if ((r & 3) == 0) la += e0 + e1;
        else if ((r & 3) == 1) lb += e0 + e1;
        else if ((r & 3) == 2) lc += e0 + e1;
        else ld += e0 + e1;
      }

      // pack + lane-half swap -> PV A-operand: row(lane&31)=q, k=8h+i per kstep
      bf16x8 pa[4];
#pragma unroll
      for (int s = 0; s < 4; s++) {
        const int o = (s & 1) * 8;
        unsigned w0, w1, w2, w3;
        if (s < 2) {
          w0 = pk2(sacc0[o + 0], sacc0[o + 1]);
          w1 = pk2(sacc0[o + 2], sacc0[o + 3]);
          w2 = pk2(sacc0[o + 4], sacc0[o + 5]);
          w3 = pk2(sacc0[o + 6], sacc0[o + 7]);
        } else {
          w0 = pk2(sacc1[o + 0], sacc1[o + 1]);
          w1 = pk2(sacc1[o + 2], sacc1[o + 3]);
          w2 = pk2(sacc1[o + 4], sacc1[o + 5]);
          w3 = pk2(sacc1[o + 6], sacc1[o + 7]);
        }
        plswap(w0, w2);  // w0={lo,lo}, w2={hi,hi}
        plswap(w1, w3);
        union { unsigned u[4]; bf16x8 v; } pu;
        pu.u[0] = w0; pu.u[1] = w1; pu.u[2] = w2; pu.u[3] = w3;
        pa[s] = pu.v;
      }

      // O[q][dh] += P * V : B=V[k][dh] from Vt LDS
      __builtin_amdgcn_s_setprio(1);
#pragma unroll
      for (int ks = 0; ks < 4; ks++) {
        const bf16x8 vf0 = *(const bf16x8*)(vb_ + base0 + co[ks]);
        const bf16x8 vf1 = *(const bf16x8*)(vb_ + base1 + co[ks]);
        of0 = __builtin_amdgcn_mfma_f32_32x32x16_bf16(pa[ks], vf0, of0, 0, 0, 0);
        of1 = __builtin_amdgcn_mfma_f32_32x32x16_bf16(pa[ks], vf1, of1, 0, 0, 0);
      }
      __builtin_amdgcn_s_setprio(0);
      __syncthreads();
      buf ^= 1;
    }
#undef STAGE

    // ---- in-kernel normalize + bf16 output ----
    // l_tot (full denominator for q=l32) on all lanes; broadcast per-q l through
    // LDS (sK area is dead: final loop barrier passed). Per-wave slice disjoint;
    // same-wave ds_write->ds_read ordering is lgkmcnt-enforced, no barrier.
    float* sLf = (float*)SH;
    const float l_lane = (la + lb) + (lc + ld);
    const float l_tot = l_lane + __shfl_xor(l_lane, 32);
    if (h == 0) sLf[wq * 32 + l32] = l_tot;
    const int b_ = bh >> 4, h_ = bh & 15;
#pragma unroll
    for (int r = 0; r < 16; r++) {
      const int row = (r & 3) + 8 * (r >> 2) + 4 * h;  // q within the wave's 32
      const float inv = 1.f / sLf[wq * 32 + row];      // broadcast read (uniform/half)
      const int qg = q0 + wq * 32 + row;
      short* d = AOb + ((size_t)(b_ * TQ + qg)) * DM + h_ * 64;
      d[l32] = f2bf(of0[r] * inv);
      d[32 + l32] = f2bf(of1[r] * inv);
    }
  } else if (bid < 8704) {
    // ---------------- expand_k role ----------------
    const size_t f4 = (size_t)(bid - 512) * 256 + threadIdx.x;
    const size_t e = f4 * 4;
    const int t = (int)((e >> 6) & 4095);
    float4 v;
    if (t < TCACHE) {
      const int dh = (int)(e & 63);
      const int bh = (int)(e >> 18);
      v = *(const float4*)(kc + ((size_t)(bh * TCACHE + t)) * DH + dh);
    } else {
      const short4 s = *(const short4*)(Kb + e);
      v.x = bf2f(s.x); v.y = bf2f(s.y); v.z = bf2f(s.z); v.w = bf2f(s.w);
    }
    *(float4*)(kF + e) = v;
  } else {
    // ---------------- expand_v role ----------------
    const int local = bid - 8704;
    const int tt = local & 63, bh = local >> 6;
    short* tile = SH;  // [64][72]
    if (tt < 32) {
#pragma unroll
      for (int k2 = 0; k2 < 4; k2++) {
        const int f = threadIdx.x + k2 * 256;
        const int trow = f >> 4, dh4 = f & 15;
        const size_t si = ((size_t)(bh * TCACHE) + tt * 64 + trow) * DH + dh4 * 4;
        const size_t di = ((size_t)(bh * TKTOT) + tt * 64 + trow) * DH + dh4 * 4;
        *(float4*)(vF + di) = *(const float4*)(vc + si);
      }
    } else {
      const int t0 = tt * 64;
#pragma unroll
      for (int k2 = 0; k2 < 4; k2++) {
        const int f = threadIdx.x + k2 * 256;
        const int dh = f >> 4, tc4 = f & 15;
        const short4 s = *(const short4*)(Vtb + ((size_t)(bh * DH + dh)) * TKTOT + t0 + tc4 * 4);
        *(short4*)(&tile[dh * 72 + tc4 * 4]) = s;
      }
      __syncthreads();
#pragma unroll
      for (int k2 = 0; k2 < 4; k2++) {
        const int f = threadIdx.x + k2 * 256;
        const int trow = f >> 4, dh4 = f & 15;
        float4 v;
        v.x = bf2f(tile[(dh4 * 4 + 0) * 72 + trow]);
        v.y = bf2f(tile[(dh4 * 4 + 1) * 72 + trow]);
        v.z = bf2f(tile[(dh4 * 4 + 2) * 72 + trow]);
        v.w = bf2f(tile[(dh4 * 4 + 3) * 72 + trow]);
        *(float4*)(vF + ((size_t)(bh * TKTOT) + t0 + trow) * DH + dh4 * 4) = v;
      }
    }
  }
}

// ---------- host ----------

extern "C" void kernel_launch(void* const* d_in, const int* in_sizes, int n_in,
                              void* d_out, int out_size, void* d_ws, size_t ws_size,
                              hipStream_t stream) {
  const float* x = (const float*)d_in[0];
  const float* kc = (const float*)d_in[1];
  const float* vc = (const float*)d_in[2];
  const float* Wq = (const float*)d_in[3];
  const float* bq = (const float*)d_in[4];
  const float* Wk = (const float*)d_in[5];
  const float* bk = (const float*)d_in[6];
  const float* Wv = (const float*)d_in[7];
  const float* bv = (const float*)d_in[8];
  const float* Wo = (const float*)d_in[9];
  const float* bo = (const float*)d_in[10];

  float* out = (float*)d_out;
  float* kF = out + (size_t)BB * TQ * DM;          // k output region (33.55 MB)
  float* vF = kF + (size_t)BB * NH * TKTOT * DH;   // v output region (33.55 MB)

  char* ws = (char*)d_ws;
  short* xb = (short*)ws;   ws += (size_t)MROWS * DM * 2;
  short* Wt = (short*)ws;   ws += (size_t)4 * DM * DM * 2;
  short* Qb = (short*)ws;   ws += (size_t)BB * NH * TQ * DH * 2;
  short* Kb = (short*)ws;   ws += (size_t)BB * NH * TKTOT * DH * 2;
  short* Vtb = (short*)ws;  ws += (size_t)BB * NH * TKTOT * DH * 2;
  short* AOb = (short*)ws;  // total ws use: 64 MiB

  k_prep<<<13312, 256, 0, stream>>>(x, xb, Wq, Wk, Wv, Wo, Wt, kc, Kb, vc, Vtb);
  k_gemm<<<dim3(DM / 128, MROWS / 128, 3), 256, 0, stream>>>(
      xb, Wt, bq, bk, bv, 1, nullptr, Qb, Kb, Vtb);
  k_attn_expand<<<10752, 256, 0, stream>>>(Qb, Kb, Vtb, AOb, kc, kF, vc, vF);
  k_gemm<<<dim3(DM / 128, MROWS / 128, 1), 256, 0, stream>>>(
      AOb, Wt + (size_t)3 * DM * DM, bo, bo, bo, 0, out, nullptr, nullptr, nullptr);
}